// Round 6
// baseline (413.700 us; speedup 1.0000x reference)
//
#include <hip/hip_runtime.h>
#include <hip/hip_bf16.h>

#define TQn 1024
#define NB  16
#define DIM 1024
#define BM  128
#define BN  128
#define BK  32
#define STR 40
#define VSTR 132

typedef __attribute__((ext_vector_type(4))) float f32x4;
typedef __attribute__((ext_vector_type(8))) short s16x8;
typedef __attribute__((ext_vector_type(4))) short s16x4;

__device__ __forceinline__ short f2bf(float f){
  union { float f; unsigned u; } v; v.f = f;
  unsigned r = v.u + 0x7fffu + ((v.u >> 16) & 1u);  // RNE
  return (short)(r >> 16);
}
__device__ __forceinline__ float bf2f(short h){
  union { unsigned u; float f; } v; v.u = ((unsigned)(unsigned short)h) << 16;
  return v.f;
}

__device__ __forceinline__ void gload16(const short* g, short* l){
#if __has_builtin(__builtin_amdgcn_global_load_lds)
  __builtin_amdgcn_global_load_lds(
      (const __attribute__((address_space(1))) unsigned int*)(const void*)g,
      (__attribute__((address_space(3))) unsigned int*)(void*)l, 16, 0, 0);
#else
  *reinterpret_cast<s16x8*>(l) = *reinterpret_cast<const s16x8*>(g);
#endif
}

// ---------------- fast path ----------------

// split fp32 -> bf16 hi/lo planes (elementwise, memory-bound)
__global__ __launch_bounds__(256) void k0_split(const float* __restrict__ in,
                                                short* __restrict__ hi,
                                                short* __restrict__ lo){
  const size_t i = ((size_t)blockIdx.x * 256 + threadIdx.x) * 4;
  f32x4 v = *reinterpret_cast<const f32x4*>(in + i);
  s16x4 h, l;
  #pragma unroll
  for (int j = 0; j < 4; ++j){ h[j] = f2bf(v[j]); l[j] = f2bf(v[j] - bf2f(h[j])); }
  *reinterpret_cast<s16x4*>(hi + i) = h;
  *reinterpret_cast<s16x4*>(lo + i) = l;
}

// values [b][s][v] fp32 -> vT [b][v][s] bf16 (tiled transpose)
__global__ __launch_bounds__(256) void k0_vtrans(const float* __restrict__ vals,
                                                 short* __restrict__ vT){
  __shared__ short T[64 * 72];
  const int t = threadIdx.x;
  const int v0 = blockIdx.x * 64, s0 = blockIdx.y * 64, b = blockIdx.z;
  const int r16 = t >> 4, c4 = (t & 15) * 4;
  #pragma unroll
  for (int i = 0; i < 4; ++i){
    const int sl = i * 16 + r16;
    f32x4 v = *reinterpret_cast<const f32x4*>(vals + ((size_t)b * TQn + s0 + sl) * DIM + v0 + c4);
    #pragma unroll
    for (int j = 0; j < 4; ++j) T[(c4 + j) * 72 + sl] = f2bf(v[j]);
  }
  __syncthreads();
  #pragma unroll
  for (int i = 0; i < 4; ++i){
    const int vl = i * 16 + r16;
    s16x4 o = *reinterpret_cast<const s16x4*>(&T[vl * 72 + c4]);
    *reinterpret_cast<s16x4*>(vT + ((size_t)b * DIM + v0 + vl) * TQn + s0 + c4) = o;
  }
}

// 256x256-tile bf16 A*B^T GEMM, 8 waves, BK=64, double-buffered LDS (128 KB),
// fragment-major layout (conflict-free b128 reads), global_load_lds staging,
// counted-vmcnt prefetch + 4-phase compute split (phase: ds_read subtile ->
// barrier -> setprio(1) -> 16 MFMA -> setprio(0) -> barrier).
// CH=3: virtual-K 3x1024 over chains (Ah*Bh + Al*Bh + Ah*Bl), CH=1: plain.
template<int CH, int EPI>
__global__ __launch_bounds__(512, 2) void gemm256(
    const short* __restrict__ Ah, const short* __restrict__ Al,
    const short* __restrict__ Bh, const short* __restrict__ Bl,
    float* __restrict__ C, short* __restrict__ Ch, short* __restrict__ Cl,
    int ARS, int ABO, int BRS, int BBO, int CBO)
{
  constexpr int NSTEP = (CH == 3) ? 48 : 16;
  __shared__ __align__(16) short lds[2 * 32768];   // 128 KB
  const int tid = threadIdx.x;
  const int lane = tid & 63, w = tid >> 6;
  const int cl = lane & 15, kg = lane >> 4;
  const int bx = blockIdx.x, by = blockIdx.y, bz = blockIdx.z;
  const int wr = w >> 2, wc = w & 3;

  // staging: waves 0-3 own the A tile (32 chunks of 512 shorts), waves 4-7 the B tile.
  const bool isA = (w < 4);
  const int RS = isA ? ARS : BRS, BO = isA ? ABO : BBO;
  const int blk0 = (isA ? by : bx) * 256;
  int offs[8];
  #pragma unroll
  for (int c = 0; c < 8; ++c){
    const int g = (w & 3) * 8 + c;
    const int row = blk0 + (g >> 1) * 16 + cl;
    offs[c] = (row * RS + bz * BO) * 1024 + (g & 1) * 32 + kg * 8;
  }
  const int sbase = (isA ? 0 : 16384) + (w & 3) * 8 * 512 + lane * 8;

  f32x4 acc[8][4] = {};

  // prologue: stage tile 0 (chain 0 -> Ah,Bh)
  {
    const short* P = isA ? Ah : Bh;
    #pragma unroll
    for (int c = 0; c < 8; ++c)
      gload16(P + (size_t)offs[c], &lds[sbase + c * 512]);
  }
  for (int t = 0; t < NSTEP; ++t){
    const int buf = (t & 1) * 32768;
    if (t + 1 < NSTEP){
      const int t1 = t + 1;
      const int cc = (CH == 3) ? (t1 % 3) : 0;
      const int k0 = ((CH == 3) ? (t1 / 3) : t1) * 64;
      const short* P = isA ? ((CH == 3 && cc == 1) ? Al : Ah)
                           : ((CH == 3 && cc == 2) ? Bl : Bh);
      const int nbuf = (t1 & 1) * 32768;
      #pragma unroll
      for (int c = 0; c < 8; ++c)
        gload16(P + (size_t)(offs[c] + k0), &lds[nbuf + sbase + c * 512]);
      asm volatile("s_waitcnt vmcnt(8)" ::: "memory");  // tile t arrived; t+1 in flight
    } else {
      asm volatile("s_waitcnt vmcnt(0)" ::: "memory");
    }
    __builtin_amdgcn_s_barrier();   // all waves' tile-t chunks landed

    s16x8 av[4], bv[4];
    #pragma unroll
    for (int h = 0; h < 2; ++h){
      // ---- phase A: B-frags for this half + A-frags m0-3 ----
      #pragma unroll
      for (int n = 0; n < 4; ++n)
        bv[n] = *reinterpret_cast<const s16x8*>(
            &lds[buf + 16384 + (((wc * 4 + n) << 1) + h) * 512 + lane * 8]);
      #pragma unroll
      for (int m = 0; m < 4; ++m)
        av[m] = *reinterpret_cast<const s16x8*>(
            &lds[buf + (((wr * 8 + m) << 1) + h) * 512 + lane * 8]);
      __builtin_amdgcn_s_barrier();
      __builtin_amdgcn_s_setprio(1);
      #pragma unroll
      for (int m = 0; m < 4; ++m)
        #pragma unroll
        for (int n = 0; n < 4; ++n)
          acc[m][n] = __builtin_amdgcn_mfma_f32_16x16x32_bf16(av[m], bv[n], acc[m][n], 0, 0, 0);
      __builtin_amdgcn_s_setprio(0);
      __builtin_amdgcn_s_barrier();
      // ---- phase B: A-frags m4-7 (bv reused) ----
      #pragma unroll
      for (int m = 0; m < 4; ++m)
        av[m] = *reinterpret_cast<const s16x8*>(
            &lds[buf + (((wr * 8 + 4 + m) << 1) + h) * 512 + lane * 8]);
      __builtin_amdgcn_s_barrier();
      __builtin_amdgcn_s_setprio(1);
      #pragma unroll
      for (int m = 0; m < 4; ++m)
        #pragma unroll
        for (int n = 0; n < 4; ++n)
          acc[4 + m][n] = __builtin_amdgcn_mfma_f32_16x16x32_bf16(av[m], bv[n], acc[4 + m][n], 0, 0, 0);
      __builtin_amdgcn_s_setprio(0);
      __builtin_amdgcn_s_barrier();
    }
  }
  #pragma unroll
  for (int m = 0; m < 8; ++m){
    const int row0 = by * 256 + wr * 128 + m * 16 + kg * 4;
    #pragma unroll
    for (int n = 0; n < 4; ++n){
      const int col = bx * 256 + wc * 64 + n * 16 + cl;
      #pragma unroll
      for (int j = 0; j < 4; ++j){
        const size_t off = ((size_t)(row0 + j) + (size_t)bz * CBO) * 1024 + col;
        if (EPI == 0) C[off] = acc[m][n][j];
        else {
          const float v = acc[m][n][j];
          const short hh = f2bf(v);
          Ch[off] = hh; Cl[off] = f2bf(v - bf2f(hh));
        }
      }
    }
  }
}

// K3: in-place row softmax of (logits + mask[b][s]); optional bf16 copy for K4
__global__ __launch_bounds__(256) void k3_softmax(float* __restrict__ logits,
                                                  const float* __restrict__ mask,
                                                  short* __restrict__ sbf){
  const int row = blockIdx.x;       // b*TQ + t
  const int b = row >> 10;
  const int tid = threadIdx.x;
  float* p = logits + (size_t)row * DIM;
  f32x4 v  = *reinterpret_cast<const f32x4*>(p + tid * 4);
  f32x4 mk = *reinterpret_cast<const f32x4*>(mask + (size_t)b * DIM + tid * 4);
  v = v + mk;
  float mx = fmaxf(fmaxf(v[0], v[1]), fmaxf(v[2], v[3]));
  #pragma unroll
  for (int off = 32; off; off >>= 1) mx = fmaxf(mx, __shfl_xor(mx, off));
  __shared__ float red[8];
  const int lane = tid & 63, wid = tid >> 6;
  if (lane == 0) red[wid] = mx;
  __syncthreads();
  mx = fmaxf(fmaxf(red[0], red[1]), fmaxf(red[2], red[3]));
  f32x4 e;
  #pragma unroll
  for (int j = 0; j < 4; ++j) e[j] = __expf(v[j] - mx);
  float s = e[0] + e[1] + e[2] + e[3];
  #pragma unroll
  for (int off = 32; off; off >>= 1) s += __shfl_xor(s, off);
  if (lane == 0) red[4 + wid] = s;
  __syncthreads();
  s = red[4] + red[5] + red[6] + red[7];
  const float inv = 1.0f / s;
  f32x4 o;
  s16x4 ob;
  #pragma unroll
  for (int j = 0; j < 4; ++j){ o[j] = e[j] * inv; ob[j] = f2bf(o[j]); }
  *reinterpret_cast<f32x4*>(p + tid * 4) = o;
  if (sbf) *reinterpret_cast<s16x4*>(sbf + (size_t)row * DIM + tid * 4) = ob;
}

// ---------------- fallback (round-3 passing) kernels ----------------

__global__ __launch_bounds__(256) void k1_qp(const float* __restrict__ A,
                                             const float* __restrict__ Wm,
                                             float* __restrict__ C){
  __shared__ __align__(16) short Ah[BM * STR];
  __shared__ __align__(16) short Al[BM * STR];
  __shared__ __align__(16) short Bh[BN * STR];
  __shared__ __align__(16) short Bl[BN * STR];
  const int tid = threadIdx.x;
  const int m0 = blockIdx.y * BM, n0 = blockIdx.x * BN;
  const int lane = tid & 63, wid = tid >> 6;
  const int wm = (wid >> 1) * 64, wn = (wid & 1) * 64;
  const int cl = lane & 15, kg = lane >> 4;
  const int rr = tid >> 3, f4 = (tid & 7) * 4;
  f32x4 acc[4][4] = {};
  for (int k0 = 0; k0 < DIM; k0 += BK){
    #pragma unroll
    for (int i = 0; i < 4; ++i){
      const int r = rr + i * 32;
      f32x4 va = *reinterpret_cast<const f32x4*>(A  + (size_t)(m0 + r) * DIM + k0 + f4);
      f32x4 vb = *reinterpret_cast<const f32x4*>(Wm + (size_t)(n0 + r) * DIM + k0 + f4);
      s16x4 ha, la, hb, lb;
      #pragma unroll
      for (int j = 0; j < 4; ++j){
        ha[j] = f2bf(va[j]); la[j] = f2bf(va[j] - bf2f(ha[j]));
        hb[j] = f2bf(vb[j]); lb[j] = f2bf(vb[j] - bf2f(hb[j]));
      }
      *reinterpret_cast<s16x4*>(&Ah[r * STR + f4]) = ha;
      *reinterpret_cast<s16x4*>(&Al[r * STR + f4]) = la;
      *reinterpret_cast<s16x4*>(&Bh[r * STR + f4]) = hb;
      *reinterpret_cast<s16x4*>(&Bl[r * STR + f4]) = lb;
    }
    __syncthreads();
    s16x8 ah[4], al8[4], bh8[4], bl8[4];
    #pragma unroll
    for (int m = 0; m < 4; ++m){
      ah[m]  = *reinterpret_cast<const s16x8*>(&Ah[(wm + m * 16 + cl) * STR + kg * 8]);
      al8[m] = *reinterpret_cast<const s16x8*>(&Al[(wm + m * 16 + cl) * STR + kg * 8]);
    }
    #pragma unroll
    for (int n = 0; n < 4; ++n){
      bh8[n] = *reinterpret_cast<const s16x8*>(&Bh[(wn + n * 16 + cl) * STR + kg * 8]);
      bl8[n] = *reinterpret_cast<const s16x8*>(&Bl[(wn + n * 16 + cl) * STR + kg * 8]);
    }
    #pragma unroll
    for (int m = 0; m < 4; ++m)
      #pragma unroll
      for (int n = 0; n < 4; ++n){
        acc[m][n] = __builtin_amdgcn_mfma_f32_16x16x32_bf16(ah[m],  bh8[n], acc[m][n], 0, 0, 0);
        acc[m][n] = __builtin_amdgcn_mfma_f32_16x16x32_bf16(al8[m], bh8[n], acc[m][n], 0, 0, 0);
        acc[m][n] = __builtin_amdgcn_mfma_f32_16x16x32_bf16(ah[m],  bl8[n], acc[m][n], 0, 0, 0);
      }
    __syncthreads();
  }
  #pragma unroll
  for (int m = 0; m < 4; ++m){
    const int row = m0 + wm + m * 16 + kg * 4;
    #pragma unroll
    for (int n = 0; n < 4; ++n){
      const int col = n0 + wn + n * 16 + cl;
      #pragma unroll
      for (int j = 0; j < 4; ++j)
        C[(size_t)(row + j) * DIM + col] = acc[m][n][j];
    }
  }
}

__global__ __launch_bounds__(256) void k2_logits(const float* __restrict__ qp,
                                                 const float* __restrict__ keys,
                                                 float* __restrict__ out){
  __shared__ __align__(16) short Ah[BM * STR];
  __shared__ __align__(16) short Al[BM * STR];
  __shared__ __align__(16) short Bh[BN * STR];
  __shared__ __align__(16) short Bl[BN * STR];
  const int tid = threadIdx.x;
  const int b = blockIdx.z;
  const int t0 = blockIdx.y * BM, s0 = blockIdx.x * BN;
  const int lane = tid & 63, wid = tid >> 6;
  const int wm = (wid >> 1) * 64, wn = (wid & 1) * 64;
  const int cl = lane & 15, kg = lane >> 4;
  const int rr = tid >> 3, f4 = (tid & 7) * 4;
  f32x4 acc[4][4] = {};
  for (int k0 = 0; k0 < DIM; k0 += BK){
    #pragma unroll
    for (int i = 0; i < 4; ++i){
      const int r = rr + i * 32;
      f32x4 va = *reinterpret_cast<const f32x4*>(qp   + (size_t)((t0 + r) * NB + b) * DIM + k0 + f4);
      f32x4 vb = *reinterpret_cast<const f32x4*>(keys + ((size_t)b * DIM + s0 + r) * DIM + k0 + f4);
      s16x4 ha, la, hb, lb;
      #pragma unroll
      for (int j = 0; j < 4; ++j){
        ha[j] = f2bf(va[j]); la[j] = f2bf(va[j] - bf2f(ha[j]));
        hb[j] = f2bf(vb[j]); lb[j] = f2bf(vb[j] - bf2f(hb[j]));
      }
      *reinterpret_cast<s16x4*>(&Ah[r * STR + f4]) = ha;
      *reinterpret_cast<s16x4*>(&Al[r * STR + f4]) = la;
      *reinterpret_cast<s16x4*>(&Bh[r * STR + f4]) = hb;
      *reinterpret_cast<s16x4*>(&Bl[r * STR + f4]) = lb;
    }
    __syncthreads();
    s16x8 ah[4], al8[4], bh8[4], bl8[4];
    #pragma unroll
    for (int m = 0; m < 4; ++m){
      ah[m]  = *reinterpret_cast<const s16x8*>(&Ah[(wm + m * 16 + cl) * STR + kg * 8]);
      al8[m] = *reinterpret_cast<const s16x8*>(&Al[(wm + m * 16 + cl) * STR + kg * 8]);
    }
    #pragma unroll
    for (int n = 0; n < 4; ++n){
      bh8[n] = *reinterpret_cast<const s16x8*>(&Bh[(wn + n * 16 + cl) * STR + kg * 8]);
      bl8[n] = *reinterpret_cast<const s16x8*>(&Bl[(wn + n * 16 + cl) * STR + kg * 8]);
    }
    #pragma unroll
    for (int m = 0; m < 4; ++m)
      #pragma unroll
      for (int n = 0; n < 4; ++n){
        acc[m][n] = __builtin_amdgcn_mfma_f32_16x16x32_bf16(ah[m],  bh8[n], acc[m][n], 0, 0, 0);
        acc[m][n] = __builtin_amdgcn_mfma_f32_16x16x32_bf16(al8[m], bh8[n], acc[m][n], 0, 0, 0);
        acc[m][n] = __builtin_amdgcn_mfma_f32_16x16x32_bf16(ah[m],  bl8[n], acc[m][n], 0, 0, 0);
      }
    __syncthreads();
  }
  #pragma unroll
  for (int m = 0; m < 4; ++m){
    const int trow = t0 + wm + m * 16 + kg * 4;
    #pragma unroll
    for (int n = 0; n < 4; ++n){
      const int scol = s0 + wn + n * 16 + cl;
      #pragma unroll
      for (int j = 0; j < 4; ++j)
        out[((size_t)b * TQn + trow + j) * DIM + scol] = acc[m][n][j];
    }
  }
}

__global__ __launch_bounds__(256) void k4_ctx(const float* __restrict__ score,
                                              const float* __restrict__ values,
                                              float* __restrict__ ctx){
  __shared__ __align__(16) short As[BM * STR];
  __shared__ __align__(16) float Vs[BK * VSTR];
  const int tid = threadIdx.x;
  const int b = blockIdx.z;
  const int t0 = blockIdx.y * BM, v0 = blockIdx.x * BN;
  const int lane = tid & 63, wid = tid >> 6;
  const int wm = (wid >> 1) * 64, wn = (wid & 1) * 64;
  const int cl = lane & 15, kg = lane >> 4;
  const int rr = tid >> 3, f4 = (tid & 7) * 4;
  const int vr = tid >> 5, vc = tid & 31;
  f32x4 acc[4][4] = {};
  for (int k0 = 0; k0 < DIM; k0 += BK){
    #pragma unroll
    for (int i = 0; i < 4; ++i){
      const int r = rr + i * 32;
      f32x4 va = *reinterpret_cast<const f32x4*>(score + ((size_t)b * TQn + t0 + r) * DIM + k0 + f4);
      s16x4 ha;
      #pragma unroll
      for (int j = 0; j < 4; ++j) ha[j] = f2bf(va[j]);
      *reinterpret_cast<s16x4*>(&As[r * STR + f4]) = ha;
      const int vrow = vr + i * 8;
      f32x4 vv = *reinterpret_cast<const f32x4*>(values + ((size_t)b * DIM + k0 + vrow) * DIM + v0 + vc * 4);
      const int cb = vc ^ (((vrow >> 3) & 1) << 2);
      *reinterpret_cast<f32x4*>(&Vs[vrow * VSTR + cb * 4]) = vv;
    }
    __syncthreads();
    s16x8 af[4], bfr[4];
    #pragma unroll
    for (int m = 0; m < 4; ++m)
      af[m] = *reinterpret_cast<const s16x8*>(&As[(wm + m * 16 + cl) * STR + kg * 8]);
    #pragma unroll
    for (int n = 0; n < 4; ++n){
      const int colb = wn + n * 16 + cl;
      const int cb = (colb >> 2) ^ ((kg & 1) << 2);
      #pragma unroll
      for (int j = 0; j < 8; ++j){
        const int rowv = kg * 8 + j;
        bfr[n][j] = f2bf(Vs[rowv * VSTR + cb * 4 + (colb & 3)]);
      }
    }
    #pragma unroll
    for (int m = 0; m < 4; ++m)
      #pragma unroll
      for (int n = 0; n < 4; ++n)
        acc[m][n] = __builtin_amdgcn_mfma_f32_16x16x32_bf16(af[m], bfr[n], acc[m][n], 0, 0, 0);
    __syncthreads();
  }
  #pragma unroll
  for (int m = 0; m < 4; ++m){
    const int trow = t0 + wm + m * 16 + kg * 4;
    #pragma unroll
    for (int n = 0; n < 4; ++n){
      const int vcol = v0 + wn + n * 16 + cl;
      #pragma unroll
      for (int j = 0; j < 4; ++j)
        ctx[((size_t)b * TQn + trow + j) * DIM + vcol] = acc[m][n][j];
    }
  }
}

extern "C" void kernel_launch(void* const* d_in, const int* in_sizes, int n_in,
                              void* d_out, int out_size, void* d_ws, size_t ws_size,
                              hipStream_t stream){
  (void)in_sizes; (void)n_in; (void)out_size;
  const float* query  = (const float*)d_in[0];  // [1024][16][1024] == m-major [16384][1024]
  const float* keys   = (const float*)d_in[1];  // [16][1024][1024]
  const float* values = (const float*)d_in[2];  // [16][1024][1024]
  const float* mask   = (const float*)d_in[3];  // [16][1024]
  const float* Wm     = (const float*)d_in[4];  // [1024][1024]
  float* score = (float*)d_out;                              // [16][1024][1024]
  float* ctx   = score + (size_t)NB * TQn * DIM;             // qp-plane scratch then real ctx
  dim3 blk(256, 1, 1);
  dim3 blk512(512, 1, 1);

  const size_t M16 = (size_t)16 * 1024 * 1024;   // 16M shorts
  const size_t M1  = (size_t)1024 * 1024;
  const size_t need = (4 * M16 + 2 * M1 + 2 * M16) * 2;   // 196 MB
  if (ws_size >= need){
    short* w  = (short*)d_ws;
    short* qh = w;                 // query hi
    short* ql = qh + M16;
    short* kh = ql + M16;          // keys hi
    short* kl = kh + M16;
    short* wh = kl + M16;          // W hi
    short* wl = wh + M1;
    short* vT = wl + M1;           // values^T bf16 [b][v][s]
    short* sb = vT + M16;          // score bf16
    short* qph = (short*)ctx;      // qp hi plane (m-major [16384][1024])
    short* qpl = qph + M16;

    k0_split<<<dim3(16384, 1, 1), blk, 0, stream>>>(query, qh, ql);
    k0_split<<<dim3(16384, 1, 1), blk, 0, stream>>>(keys, kh, kl);
    k0_split<<<dim3(1024, 1, 1), blk, 0, stream>>>(Wm, wh, wl);
    k0_vtrans<<<dim3(16, 16, 16), blk, 0, stream>>>(values, vT);
    // K1: qp = query . W^T -> bf16 hi/lo planes (M=16384, N=1024)
    gemm256<3, 1><<<dim3(4, 64, 1), blk512, 0, stream>>>(qh, ql, wh, wl,
        nullptr, qph, qpl, 1, 0, 1, 0, 0);
    // K2: logits[b][t][s] = qp[t*16+b][:] . keys[b][s][:]
    gemm256<3, 0><<<dim3(4, 4, 16), blk512, 0, stream>>>(qph, qpl, kh, kl,
        score, nullptr, nullptr, 16, 1, 1, 1024, 1024);
    k3_softmax<<<dim3(NB * TQn, 1, 1), blk, 0, stream>>>(score, mask, sb);
    // K4: ctx[b][t][v] = score[b][t][:] . vT[b][v][:]
    gemm256<1, 0><<<dim3(4, 4, 16), blk512, 0, stream>>>(sb, nullptr, vT, nullptr,
        ctx, nullptr, nullptr, 1, 1024, 1, 1024, 1024);
  } else {
    k1_qp<<<dim3(DIM / BN, (TQn * NB) / BM, 1), blk, 0, stream>>>(query, Wm, ctx);
    k2_logits<<<dim3(DIM / BN, TQn / BM, NB), blk, 0, stream>>>(ctx, keys, score);
    k3_softmax<<<dim3(NB * TQn, 1, 1), blk, 0, stream>>>(score, mask, nullptr);
    k4_ctx<<<dim3(DIM / BN, TQn / BM, NB), blk, 0, stream>>>(score, values, ctx);
  }
}

// Round 7
// 399.491 us; speedup vs baseline: 1.0356x; 1.0356x over previous
//
#include <hip/hip_runtime.h>
#include <hip/hip_bf16.h>

#define TQn 1024
#define NB  16
#define DIM 1024
#define BM  128
#define BN  128
#define BK  32
#define STR 40
#define VSTR 132

typedef __attribute__((ext_vector_type(4))) float f32x4;
typedef __attribute__((ext_vector_type(8))) short s16x8;
typedef __attribute__((ext_vector_type(4))) short s16x4;

__device__ __forceinline__ short f2bf(float f){
  union { float f; unsigned u; } v; v.f = f;
  unsigned r = v.u + 0x7fffu + ((v.u >> 16) & 1u);  // RNE
  return (short)(r >> 16);
}
__device__ __forceinline__ float bf2f(short h){
  union { unsigned u; float f; } v; v.u = ((unsigned)(unsigned short)h) << 16;
  return v.f;
}

__device__ __forceinline__ void gload16(const short* g, short* l){
#if __has_builtin(__builtin_amdgcn_global_load_lds)
  __builtin_amdgcn_global_load_lds(
      (const __attribute__((address_space(1))) unsigned int*)(const void*)g,
      (__attribute__((address_space(3))) unsigned int*)(void*)l, 16, 0, 0);
#else
  *reinterpret_cast<s16x8*>(l) = *reinterpret_cast<const s16x8*>(g);
#endif
}

// ---------------- fast path ----------------

__global__ __launch_bounds__(256) void k0_split(const float* __restrict__ in,
                                                short* __restrict__ hi,
                                                short* __restrict__ lo){
  const size_t i = ((size_t)blockIdx.x * 256 + threadIdx.x) * 4;
  f32x4 v = *reinterpret_cast<const f32x4*>(in + i);
  s16x4 h, l;
  #pragma unroll
  for (int j = 0; j < 4; ++j){ h[j] = f2bf(v[j]); l[j] = f2bf(v[j] - bf2f(h[j])); }
  *reinterpret_cast<s16x4*>(hi + i) = h;
  *reinterpret_cast<s16x4*>(lo + i) = l;
}

__global__ __launch_bounds__(256) void k0_vtrans(const float* __restrict__ vals,
                                                 short* __restrict__ vT){
  __shared__ short T[64 * 72];
  const int t = threadIdx.x;
  const int v0 = blockIdx.x * 64, s0 = blockIdx.y * 64, b = blockIdx.z;
  const int r16 = t >> 4, c4 = (t & 15) * 4;
  #pragma unroll
  for (int i = 0; i < 4; ++i){
    const int sl = i * 16 + r16;
    f32x4 v = *reinterpret_cast<const f32x4*>(vals + ((size_t)b * TQn + s0 + sl) * DIM + v0 + c4);
    #pragma unroll
    for (int j = 0; j < 4; ++j) T[(c4 + j) * 72 + sl] = f2bf(v[j]);
  }
  __syncthreads();
  #pragma unroll
  for (int i = 0; i < 4; ++i){
    const int vl = i * 16 + r16;
    s16x4 o = *reinterpret_cast<const s16x4*>(&T[vl * 72 + c4]);
    *reinterpret_cast<s16x4*>(vT + ((size_t)b * DIM + v0 + vl) * TQn + s0 + c4) = o;
  }
}

// 256x256 bf16 A*B^T GEMM, 8 waves (2Mx4N), BK=64, dbuf LDS 128KB, fragment-major
// (conflict-free b128), m201-style 4-phase schedule per K-tile:
//   p0: ds_read A[kk0](8)+B[kk0,n01](2); issue 4 A-stage loads(t+1); bar; prio1; 16 MFMA; prio0; bar
//   p1: ds_read B[kk0,n23](2);           issue 4 B-stage loads(t+1); bar; prio1; 16 MFMA; prio0; bar
//   p2: ds_read A[kk1](8)+B[kk1,n01](2);                             bar; prio1; 16 MFMA; prio0; bar
//   p3: ds_read B[kk1,n23](2);                                       bar; prio1; 16 MFMA; prio0;
//       vmcnt(0) [cheap: loads >=2 phases old]; bar   <- publishes staged tile t+1 to all waves
// CH=3: virtual-K 3x1024 chains (Ah*Bh + Al*Bh + Ah*Bl); CH=1: plain.
template<int CH, int EPI>
__global__ __launch_bounds__(512, 2) void gemm256(
    const short* __restrict__ Ah, const short* __restrict__ Al,
    const short* __restrict__ Bh, const short* __restrict__ Bl,
    float* __restrict__ C, short* __restrict__ Ch, short* __restrict__ Cl,
    int ARS, int ABO, int BRS, int BBO, int CBO)
{
  constexpr int NSTEP = (CH == 3) ? 48 : 16;
  __shared__ __align__(16) short lds[2 * 32768];   // 128 KB
  const int tid = threadIdx.x;
  const int lane = tid & 63, w = tid >> 6;
  const int cl = lane & 15, kg = lane >> 4;
  const int bx = blockIdx.x, by = blockIdx.y, bz = blockIdx.z;
  const int wr = w >> 2, wc = w & 3;

  // staging offsets: each wave stages 4 A-chunks (p0) and 4 B-chunks (p1) per K-tile.
  int aoff[4], boff[4], alds[4], blds[4];
  #pragma unroll
  for (int l = 0; l < 4; ++l){
    const int g = (l >> 1) * 16 + w * 2 + (l & 1);   // chunk index within tile (0..31)
    const int arow = by * 256 + (g >> 1) * 16 + cl;
    const int brow = bx * 256 + (g >> 1) * 16 + cl;
    const int kin = (g & 1) * 32 + kg * 8;
    aoff[l] = (arow * ARS + bz * ABO) * 1024 + kin;
    boff[l] = (brow * BRS + bz * BBO) * 1024 + kin;
    alds[l] = g * 512 + lane * 8;
    blds[l] = 16384 + g * 512 + lane * 8;
  }

  f32x4 acc[8][4] = {};

  // prologue: stage tile 0 (chain 0 -> Ah,Bh) into buf0, publish.
  #pragma unroll
  for (int l = 0; l < 4; ++l) gload16(Ah + (size_t)aoff[l], &lds[alds[l]]);
  #pragma unroll
  for (int l = 0; l < 4; ++l) gload16(Bh + (size_t)boff[l], &lds[blds[l]]);
  asm volatile("s_waitcnt vmcnt(0)" ::: "memory");
  __builtin_amdgcn_s_barrier();
  __builtin_amdgcn_sched_barrier(0);

  for (int t = 0; t < NSTEP; ++t){
    const int buf = (t & 1) * 32768;
    const int nbuf = 32768 - buf;
    const bool pf = (t + 1 < NSTEP);
    int k1 = 0; const short *PA = Ah, *PB = Bh;
    if (pf){
      if (CH == 3){
        const int cc = (t + 1) % 3;
        k1 = ((t + 1) / 3) * 64;
        PA = (cc == 1) ? Al : Ah;
        PB = (cc == 2) ? Bl : Bh;
      } else k1 = (t + 1) * 64;
    }

    s16x8 av[8], bv[2];
    // ---- phase 0: kk=0, n0-1 ----
    #pragma unroll
    for (int m = 0; m < 8; ++m)
      av[m] = *reinterpret_cast<const s16x8*>(&lds[buf + ((wr * 8 + m) * 2 + 0) * 512 + lane * 8]);
    #pragma unroll
    for (int n = 0; n < 2; ++n)
      bv[n] = *reinterpret_cast<const s16x8*>(&lds[buf + 16384 + ((wc * 4 + n) * 2 + 0) * 512 + lane * 8]);
    if (pf){
      #pragma unroll
      for (int l = 0; l < 4; ++l) gload16(PA + (size_t)(aoff[l] + k1), &lds[nbuf + alds[l]]);
    }
    __builtin_amdgcn_s_barrier();
    __builtin_amdgcn_s_setprio(1);
    #pragma unroll
    for (int m = 0; m < 8; ++m)
      #pragma unroll
      for (int n = 0; n < 2; ++n)
        acc[m][n] = __builtin_amdgcn_mfma_f32_16x16x32_bf16(av[m], bv[n], acc[m][n], 0, 0, 0);
    __builtin_amdgcn_s_setprio(0);
    __builtin_amdgcn_s_barrier();
    // ---- phase 1: kk=0, n2-3 (av reused) ----
    #pragma unroll
    for (int n = 0; n < 2; ++n)
      bv[n] = *reinterpret_cast<const s16x8*>(&lds[buf + 16384 + ((wc * 4 + 2 + n) * 2 + 0) * 512 + lane * 8]);
    if (pf){
      #pragma unroll
      for (int l = 0; l < 4; ++l) gload16(PB + (size_t)(boff[l] + k1), &lds[nbuf + blds[l]]);
    }
    __builtin_amdgcn_s_barrier();
    __builtin_amdgcn_s_setprio(1);
    #pragma unroll
    for (int m = 0; m < 8; ++m)
      #pragma unroll
      for (int n = 0; n < 2; ++n)
        acc[m][2 + n] = __builtin_amdgcn_mfma_f32_16x16x32_bf16(av[m], bv[n], acc[m][2 + n], 0, 0, 0);
    __builtin_amdgcn_s_setprio(0);
    __builtin_amdgcn_s_barrier();
    // ---- phase 2: kk=1, n0-1 ----
    #pragma unroll
    for (int m = 0; m < 8; ++m)
      av[m] = *reinterpret_cast<const s16x8*>(&lds[buf + ((wr * 8 + m) * 2 + 1) * 512 + lane * 8]);
    #pragma unroll
    for (int n = 0; n < 2; ++n)
      bv[n] = *reinterpret_cast<const s16x8*>(&lds[buf + 16384 + ((wc * 4 + n) * 2 + 1) * 512 + lane * 8]);
    __builtin_amdgcn_s_barrier();
    __builtin_amdgcn_s_setprio(1);
    #pragma unroll
    for (int m = 0; m < 8; ++m)
      #pragma unroll
      for (int n = 0; n < 2; ++n)
        acc[m][n] = __builtin_amdgcn_mfma_f32_16x16x32_bf16(av[m], bv[n], acc[m][n], 0, 0, 0);
    __builtin_amdgcn_s_setprio(0);
    __builtin_amdgcn_s_barrier();
    // ---- phase 3: kk=1, n2-3 ----
    #pragma unroll
    for (int n = 0; n < 2; ++n)
      bv[n] = *reinterpret_cast<const s16x8*>(&lds[buf + 16384 + ((wc * 4 + 2 + n) * 2 + 1) * 512 + lane * 8]);
    __builtin_amdgcn_s_barrier();
    __builtin_amdgcn_s_setprio(1);
    #pragma unroll
    for (int m = 0; m < 8; ++m)
      #pragma unroll
      for (int n = 0; n < 2; ++n)
        acc[m][2 + n] = __builtin_amdgcn_mfma_f32_16x16x32_bf16(av[m], bv[n], acc[m][2 + n], 0, 0, 0);
    __builtin_amdgcn_s_setprio(0);
    if (pf){
      asm volatile("s_waitcnt vmcnt(0)" ::: "memory");  // t+1 staged >=2 phases ago
      __builtin_amdgcn_s_barrier();                     // publish to all waves
      __builtin_amdgcn_sched_barrier(0);
    }
  }

  #pragma unroll
  for (int m = 0; m < 8; ++m){
    const int row0 = by * 256 + wr * 128 + m * 16 + kg * 4;
    #pragma unroll
    for (int n = 0; n < 4; ++n){
      const int col = bx * 256 + wc * 64 + n * 16 + cl;
      #pragma unroll
      for (int j = 0; j < 4; ++j){
        const size_t off = ((size_t)(row0 + j) + (size_t)bz * CBO) * 1024 + col;
        if (EPI == 0) C[off] = acc[m][n][j];
        else {
          const float v = acc[m][n][j];
          const short hh = f2bf(v);
          Ch[off] = hh; Cl[off] = f2bf(v - bf2f(hh));
        }
      }
    }
  }
}

// K3: in-place row softmax of (logits + mask[b][s]); optional bf16 copy for K4
__global__ __launch_bounds__(256) void k3_softmax(float* __restrict__ logits,
                                                  const float* __restrict__ mask,
                                                  short* __restrict__ sbf){
  const int row = blockIdx.x;       // b*TQ + t
  const int b = row >> 10;
  const int tid = threadIdx.x;
  float* p = logits + (size_t)row * DIM;
  f32x4 v  = *reinterpret_cast<const f32x4*>(p + tid * 4);
  f32x4 mk = *reinterpret_cast<const f32x4*>(mask + (size_t)b * DIM + tid * 4);
  v = v + mk;
  float mx = fmaxf(fmaxf(v[0], v[1]), fmaxf(v[2], v[3]));
  #pragma unroll
  for (int off = 32; off; off >>= 1) mx = fmaxf(mx, __shfl_xor(mx, off));
  __shared__ float red[8];
  const int lane = tid & 63, wid = tid >> 6;
  if (lane == 0) red[wid] = mx;
  __syncthreads();
  mx = fmaxf(fmaxf(red[0], red[1]), fmaxf(red[2], red[3]));
  f32x4 e;
  #pragma unroll
  for (int j = 0; j < 4; ++j) e[j] = __expf(v[j] - mx);
  float s = e[0] + e[1] + e[2] + e[3];
  #pragma unroll
  for (int off = 32; off; off >>= 1) s += __shfl_xor(s, off);
  if (lane == 0) red[4 + wid] = s;
  __syncthreads();
  s = red[4] + red[5] + red[6] + red[7];
  const float inv = 1.0f / s;
  f32x4 o;
  s16x4 ob;
  #pragma unroll
  for (int j = 0; j < 4; ++j){ o[j] = e[j] * inv; ob[j] = f2bf(o[j]); }
  *reinterpret_cast<f32x4*>(p + tid * 4) = o;
  if (sbf) *reinterpret_cast<s16x4*>(sbf + (size_t)row * DIM + tid * 4) = ob;
}

// ---------------- fallback (round-3 passing) kernels ----------------

__global__ __launch_bounds__(256) void k1_qp(const float* __restrict__ A,
                                             const float* __restrict__ Wm,
                                             float* __restrict__ C){
  __shared__ __align__(16) short Ah[BM * STR];
  __shared__ __align__(16) short Al[BM * STR];
  __shared__ __align__(16) short Bh[BN * STR];
  __shared__ __align__(16) short Bl[BN * STR];
  const int tid = threadIdx.x;
  const int m0 = blockIdx.y * BM, n0 = blockIdx.x * BN;
  const int lane = tid & 63, wid = tid >> 6;
  const int wm = (wid >> 1) * 64, wn = (wid & 1) * 64;
  const int cl = lane & 15, kg = lane >> 4;
  const int rr = tid >> 3, f4 = (tid & 7) * 4;
  f32x4 acc[4][4] = {};
  for (int k0 = 0; k0 < DIM; k0 += BK){
    #pragma unroll
    for (int i = 0; i < 4; ++i){
      const int r = rr + i * 32;
      f32x4 va = *reinterpret_cast<const f32x4*>(A  + (size_t)(m0 + r) * DIM + k0 + f4);
      f32x4 vb = *reinterpret_cast<const f32x4*>(Wm + (size_t)(n0 + r) * DIM + k0 + f4);
      s16x4 ha, la, hb, lb;
      #pragma unroll
      for (int j = 0; j < 4; ++j){
        ha[j] = f2bf(va[j]); la[j] = f2bf(va[j] - bf2f(ha[j]));
        hb[j] = f2bf(vb[j]); lb[j] = f2bf(vb[j] - bf2f(hb[j]));
      }
      *reinterpret_cast<s16x4*>(&Ah[r * STR + f4]) = ha;
      *reinterpret_cast<s16x4*>(&Al[r * STR + f4]) = la;
      *reinterpret_cast<s16x4*>(&Bh[r * STR + f4]) = hb;
      *reinterpret_cast<s16x4*>(&Bl[r * STR + f4]) = lb;
    }
    __syncthreads();
    s16x8 ah[4], al8[4], bh8[4], bl8[4];
    #pragma unroll
    for (int m = 0; m < 4; ++m){
      ah[m]  = *reinterpret_cast<const s16x8*>(&Ah[(wm + m * 16 + cl) * STR + kg * 8]);
      al8[m] = *reinterpret_cast<const s16x8*>(&Al[(wm + m * 16 + cl) * STR + kg * 8]);
    }
    #pragma unroll
    for (int n = 0; n < 4; ++n){
      bh8[n] = *reinterpret_cast<const s16x8*>(&Bh[(wn + n * 16 + cl) * STR + kg * 8]);
      bl8[n] = *reinterpret_cast<const s16x8*>(&Bl[(wn + n * 16 + cl) * STR + kg * 8]);
    }
    #pragma unroll
    for (int m = 0; m < 4; ++m)
      #pragma unroll
      for (int n = 0; n < 4; ++n){
        acc[m][n] = __builtin_amdgcn_mfma_f32_16x16x32_bf16(ah[m],  bh8[n], acc[m][n], 0, 0, 0);
        acc[m][n] = __builtin_amdgcn_mfma_f32_16x16x32_bf16(al8[m], bh8[n], acc[m][n], 0, 0, 0);
        acc[m][n] = __builtin_amdgcn_mfma_f32_16x16x32_bf16(ah[m],  bl8[n], acc[m][n], 0, 0, 0);
      }
    __syncthreads();
  }
  #pragma unroll
  for (int m = 0; m < 4; ++m){
    const int row = m0 + wm + m * 16 + kg * 4;
    #pragma unroll
    for (int n = 0; n < 4; ++n){
      const int col = n0 + wn + n * 16 + cl;
      #pragma unroll
      for (int j = 0; j < 4; ++j)
        C[(size_t)(row + j) * DIM + col] = acc[m][n][j];
    }
  }
}

__global__ __launch_bounds__(256) void k2_logits(const float* __restrict__ qp,
                                                 const float* __restrict__ keys,
                                                 float* __restrict__ out){
  __shared__ __align__(16) short Ah[BM * STR];
  __shared__ __align__(16) short Al[BM * STR];
  __shared__ __align__(16) short Bh[BN * STR];
  __shared__ __align__(16) short Bl[BN * STR];
  const int tid = threadIdx.x;
  const int b = blockIdx.z;
  const int t0 = blockIdx.y * BM, s0 = blockIdx.x * BN;
  const int lane = tid & 63, wid = tid >> 6;
  const int wm = (wid >> 1) * 64, wn = (wid & 1) * 64;
  const int cl = lane & 15, kg = lane >> 4;
  const int rr = tid >> 3, f4 = (tid & 7) * 4;
  f32x4 acc[4][4] = {};
  for (int k0 = 0; k0 < DIM; k0 += BK){
    #pragma unroll
    for (int i = 0; i < 4; ++i){
      const int r = rr + i * 32;
      f32x4 va = *reinterpret_cast<const f32x4*>(qp   + (size_t)((t0 + r) * NB + b) * DIM + k0 + f4);
      f32x4 vb = *reinterpret_cast<const f32x4*>(keys + ((size_t)b * DIM + s0 + r) * DIM + k0 + f4);
      s16x4 ha, la, hb, lb;
      #pragma unroll
      for (int j = 0; j < 4; ++j){
        ha[j] = f2bf(va[j]); la[j] = f2bf(va[j] - bf2f(ha[j]));
        hb[j] = f2bf(vb[j]); lb[j] = f2bf(vb[j] - bf2f(hb[j]));
      }
      *reinterpret_cast<s16x4*>(&Ah[r * STR + f4]) = ha;
      *reinterpret_cast<s16x4*>(&Al[r * STR + f4]) = la;
      *reinterpret_cast<s16x4*>(&Bh[r * STR + f4]) = hb;
      *reinterpret_cast<s16x4*>(&Bl[r * STR + f4]) = lb;
    }
    __syncthreads();
    s16x8 ah[4], al8[4], bh8[4], bl8[4];
    #pragma unroll
    for (int m = 0; m < 4; ++m){
      ah[m]  = *reinterpret_cast<const s16x8*>(&Ah[(wm + m * 16 + cl) * STR + kg * 8]);
      al8[m] = *reinterpret_cast<const s16x8*>(&Al[(wm + m * 16 + cl) * STR + kg * 8]);
    }
    #pragma unroll
    for (int n = 0; n < 4; ++n){
      bh8[n] = *reinterpret_cast<const s16x8*>(&Bh[(wn + n * 16 + cl) * STR + kg * 8]);
      bl8[n] = *reinterpret_cast<const s16x8*>(&Bl[(wn + n * 16 + cl) * STR + kg * 8]);
    }
    #pragma unroll
    for (int m = 0; m < 4; ++m)
      #pragma unroll
      for (int n = 0; n < 4; ++n){
        acc[m][n] = __builtin_amdgcn_mfma_f32_16x16x32_bf16(ah[m],  bh8[n], acc[m][n], 0, 0, 0);
        acc[m][n] = __builtin_amdgcn_mfma_f32_16x16x32_bf16(al8[m], bh8[n], acc[m][n], 0, 0, 0);
        acc[m][n] = __builtin_amdgcn_mfma_f32_16x16x32_bf16(ah[m],  bl8[n], acc[m][n], 0, 0, 0);
      }
    __syncthreads();
  }
  #pragma unroll
  for (int m = 0; m < 4; ++m){
    const int trow = t0 + wm + m * 16 + kg * 4;
    #pragma unroll
    for (int n = 0; n < 4; ++n){
      const int scol = s0 + wn + n * 16 + cl;
      #pragma unroll
      for (int j = 0; j < 4; ++j)
        out[((size_t)b * TQn + trow + j) * DIM + scol] = acc[m][n][j];
    }
  }
}

__global__ __launch_bounds__(256) void k4_ctx(const float* __restrict__ score,
                                              const float* __restrict__ values,
                                              float* __restrict__ ctx){
  __shared__ __align__(16) short As[BM * STR];
  __shared__ __align__(16) float Vs[BK * VSTR];
  const int tid = threadIdx.x;
  const int b = blockIdx.z;
  const int t0 = blockIdx.y * BM, v0 = blockIdx.x * BN;
  const int lane = tid & 63, wid = tid >> 6;
  const int wm = (wid >> 1) * 64, wn = (wid & 1) * 64;
  const int cl = lane & 15, kg = lane >> 4;
  const int rr = tid >> 3, f4 = (tid & 7) * 4;
  const int vr = tid >> 5, vc = tid & 31;
  f32x4 acc[4][4] = {};
  for (int k0 = 0; k0 < DIM; k0 += BK){
    #pragma unroll
    for (int i = 0; i < 4; ++i){
      const int r = rr + i * 32;
      f32x4 va = *reinterpret_cast<const f32x4*>(score + ((size_t)b * TQn + t0 + r) * DIM + k0 + f4);
      s16x4 ha;
      #pragma unroll
      for (int j = 0; j < 4; ++j) ha[j] = f2bf(va[j]);
      *reinterpret_cast<s16x4*>(&As[r * STR + f4]) = ha;
      const int vrow = vr + i * 8;
      f32x4 vv = *reinterpret_cast<const f32x4*>(values + ((size_t)b * DIM + k0 + vrow) * DIM + v0 + vc * 4);
      const int cb = vc ^ (((vrow >> 3) & 1) << 2);
      *reinterpret_cast<f32x4*>(&Vs[vrow * VSTR + cb * 4]) = vv;
    }
    __syncthreads();
    s16x8 af[4], bfr[4];
    #pragma unroll
    for (int m = 0; m < 4; ++m)
      af[m] = *reinterpret_cast<const s16x8*>(&As[(wm + m * 16 + cl) * STR + kg * 8]);
    #pragma unroll
    for (int n = 0; n < 4; ++n){
      const int colb = wn + n * 16 + cl;
      const int cb = (colb >> 2) ^ ((kg & 1) << 2);
      #pragma unroll
      for (int j = 0; j < 8; ++j){
        const int rowv = kg * 8 + j;
        bfr[n][j] = f2bf(Vs[rowv * VSTR + cb * 4 + (colb & 3)]);
      }
    }
    #pragma unroll
    for (int m = 0; m < 4; ++m)
      #pragma unroll
      for (int n = 0; n < 4; ++n)
        acc[m][n] = __builtin_amdgcn_mfma_f32_16x16x32_bf16(af[m], bfr[n], acc[m][n], 0, 0, 0);
    __syncthreads();
  }
  #pragma unroll
  for (int m = 0; m < 4; ++m){
    const int trow = t0 + wm + m * 16 + kg * 4;
    #pragma unroll
    for (int n = 0; n < 4; ++n){
      const int vcol = v0 + wn + n * 16 + cl;
      #pragma unroll
      for (int j = 0; j < 4; ++j)
        ctx[((size_t)b * TQn + trow + j) * DIM + vcol] = acc[m][n][j];
    }
  }
}

extern "C" void kernel_launch(void* const* d_in, const int* in_sizes, int n_in,
                              void* d_out, int out_size, void* d_ws, size_t ws_size,
                              hipStream_t stream){
  (void)in_sizes; (void)n_in; (void)out_size;
  const float* query  = (const float*)d_in[0];  // [1024][16][1024] == m-major [16384][1024]
  const float* keys   = (const float*)d_in[1];  // [16][1024][1024]
  const float* values = (const float*)d_in[2];  // [16][1024][1024]
  const float* mask   = (const float*)d_in[3];  // [16][1024]
  const float* Wm     = (const float*)d_in[4];  // [1024][1024]
  float* score = (float*)d_out;                              // [16][1024][1024]
  float* ctx   = score + (size_t)NB * TQn * DIM;             // qp-plane scratch then real ctx
  dim3 blk(256, 1, 1);
  dim3 blk512(512, 1, 1);

  const size_t M16 = (size_t)16 * 1024 * 1024;   // 16M shorts
  const size_t M1  = (size_t)1024 * 1024;
  const size_t need = (4 * M16 + 2 * M1 + 2 * M16) * 2;   // 196 MB
  if (ws_size >= need){
    short* w  = (short*)d_ws;
    short* qh = w;                 // query hi
    short* ql = qh + M16;
    short* kh = ql + M16;          // keys hi
    short* kl = kh + M16;
    short* wh = kl + M16;          // W hi
    short* wl = wh + M1;
    short* vT = wl + M1;           // values^T bf16 [b][v][s]
    short* sb = vT + M16;          // score bf16
    short* qph = (short*)ctx;      // qp hi plane (m-major [16384][1024])
    short* qpl = qph + M16;

    k0_split<<<dim3(16384, 1, 1), blk, 0, stream>>>(query, qh, ql);
    k0_split<<<dim3(16384, 1, 1), blk, 0, stream>>>(keys, kh, kl);
    k0_split<<<dim3(1024, 1, 1), blk, 0, stream>>>(Wm, wh, wl);
    k0_vtrans<<<dim3(16, 16, 16), blk, 0, stream>>>(values, vT);
    // K1: qp = query . W^T -> bf16 hi/lo planes (M=16384, N=1024)
    gemm256<3, 1><<<dim3(4, 64, 1), blk512, 0, stream>>>(qh, ql, wh, wl,
        nullptr, qph, qpl, 1, 0, 1, 0, 0);
    // K2: logits[b][t][s] = qp[t*16+b][:] . keys[b][s][:]
    gemm256<3, 0><<<dim3(4, 4, 16), blk512, 0, stream>>>(qph, qpl, kh, kl,
        score, nullptr, nullptr, 16, 1, 1, 1024, 1024);
    k3_softmax<<<dim3(NB * TQn, 1, 1), blk, 0, stream>>>(score, mask, sb);
    // K4: ctx[b][t][v] = score[b][t][:] . vT[b][v][:]
    gemm256<1, 0><<<dim3(4, 4, 16), blk512, 0, stream>>>(sb, nullptr, vT, nullptr,
        ctx, nullptr, nullptr, 1, 1024, 1, 1024, 1024);
  } else {
    k1_qp<<<dim3(DIM / BN, (TQn * NB) / BM, 1), blk, 0, stream>>>(query, Wm, ctx);
    k2_logits<<<dim3(DIM / BN, TQn / BM, NB), blk, 0, stream>>>(ctx, keys, score);
    k3_softmax<<<dim3(NB * TQn, 1, 1), blk, 0, stream>>>(score, mask, nullptr);
    k4_ctx<<<dim3(DIM / BN, TQn / BM, NB), blk, 0, stream>>>(score, values, ctx);
  }
}

// Round 8
// 369.822 us; speedup vs baseline: 1.1186x; 1.0802x over previous
//
#include <hip/hip_runtime.h>
#include <hip/hip_bf16.h>

#define TQn 1024
#define NB  16
#define DIM 1024
#define BM  128
#define BN  128
#define BK  32
#define STR 40
#define VSTR 132

typedef __attribute__((ext_vector_type(4))) float f32x4;
typedef __attribute__((ext_vector_type(8))) short s16x8;
typedef __attribute__((ext_vector_type(4))) short s16x4;

__device__ __forceinline__ short f2bf(float f){
  union { float f; unsigned u; } v; v.f = f;
  unsigned r = v.u + 0x7fffu + ((v.u >> 16) & 1u);  // RNE
  return (short)(r >> 16);
}
__device__ __forceinline__ float bf2f(short h){
  union { unsigned u; float f; } v; v.u = ((unsigned)(unsigned short)h) << 16;
  return v.f;
}

__device__ __forceinline__ void gload16(const short* g, short* l){
#if __has_builtin(__builtin_amdgcn_global_load_lds)
  __builtin_amdgcn_global_load_lds(
      (const __attribute__((address_space(1))) unsigned int*)(const void*)g,
      (__attribute__((address_space(3))) unsigned int*)(void*)l, 16, 0, 0);
#else
  *reinterpret_cast<s16x8*>(l) = *reinterpret_cast<const s16x8*>(g);
#endif
}

// ---------------- fast path ----------------

__global__ __launch_bounds__(256) void k0_split(const float* __restrict__ in,
                                                short* __restrict__ hi,
                                                short* __restrict__ lo){
  const size_t i = ((size_t)blockIdx.x * 256 + threadIdx.x) * 4;
  f32x4 v = *reinterpret_cast<const f32x4*>(in + i);
  s16x4 h, l;
  #pragma unroll
  for (int j = 0; j < 4; ++j){ h[j] = f2bf(v[j]); l[j] = f2bf(v[j] - bf2f(h[j])); }
  *reinterpret_cast<s16x4*>(hi + i) = h;
  *reinterpret_cast<s16x4*>(lo + i) = l;
}

__global__ __launch_bounds__(256) void k0_vtrans(const float* __restrict__ vals,
                                                 short* __restrict__ vT){
  __shared__ short T[64 * 72];
  const int t = threadIdx.x;
  const int v0 = blockIdx.x * 64, s0 = blockIdx.y * 64, b = blockIdx.z;
  const int r16 = t >> 4, c4 = (t & 15) * 4;
  #pragma unroll
  for (int i = 0; i < 4; ++i){
    const int sl = i * 16 + r16;
    f32x4 v = *reinterpret_cast<const f32x4*>(vals + ((size_t)b * TQn + s0 + sl) * DIM + v0 + c4);
    #pragma unroll
    for (int j = 0; j < 4; ++j) T[(c4 + j) * 72 + sl] = f2bf(v[j]);
  }
  __syncthreads();
  #pragma unroll
  for (int i = 0; i < 4; ++i){
    const int vl = i * 16 + r16;
    s16x4 o = *reinterpret_cast<const s16x4*>(&T[vl * 72 + c4]);
    *reinterpret_cast<s16x4*>(vT + ((size_t)b * DIM + v0 + vl) * TQn + s0 + c4) = o;
  }
}

// 256x256 bf16 A*B^T GEMM, 8 waves (2Mx4N), BK=64, dbuf 128KB, fragment-major
// (conflict-free b128). Counted-vmcnt pipeline (T4): stage 2 chunks/phase for
// tile t+1 in deadline order {ph0:B-kk0, ph1:A-kk0, ph2:B-kk1, ph3:A-kk1};
// vmcnt(4) ONLY at end-ph1 and end-ph3 (proves the 4 oldest of 8 outstanding
// landed = exactly the data read in the next two phases; never drained to 0).
// Phases compute quadrants (m03,kk0)/(m47,kk0)/(m03,kk1)/(m47,kk1), 16 MFMA
// each, wrapped in setprio(1)/(0) between two barriers.
// CH=3: virtual-K 3x1024 chains (Ah*Bh + Al*Bh + Ah*Bl); CH=1: plain.
template<int CH, int EPI>
__global__ __launch_bounds__(512, 2) void gemm256(
    const short* __restrict__ Ah, const short* __restrict__ Al,
    const short* __restrict__ Bh, const short* __restrict__ Bl,
    float* __restrict__ C, short* __restrict__ Ch, short* __restrict__ Cl,
    int ARS, int ABO, int BRS, int BBO, int CBO)
{
  constexpr int NSTEP = (CH == 3) ? 48 : 16;
  __shared__ __align__(16) short lds[2 * 32768];   // 128 KB
  const int tid = threadIdx.x;
  const int lane = tid & 63, w = tid >> 6;
  const int cl = lane & 15, kg = lane >> 4;
  const int lane8 = lane * 8;
  const int bx = blockIdx.x, by = blockIdx.y, bz = blockIdx.z;
  const int wr = w >> 2, wc = w & 3;

  // per-wave stage chunks: even chunks g = 4w, 4w+2 (kk0); odd = +1 (kk1, +32 elems)
  int aoffE[2], boffE[2], aldsE[2], bldsE[2];
  #pragma unroll
  for (int l = 0; l < 2; ++l){
    const int rg = 2 * w + l;                       // row-group (g>>1)
    const int arow = by * 256 + rg * 16 + cl;
    const int brow = bx * 256 + rg * 16 + cl;
    aoffE[l] = (arow * ARS + bz * ABO) * 1024 + kg * 8;
    boffE[l] = (brow * BRS + bz * BBO) * 1024 + kg * 8;
    aldsE[l] = (4 * w + 2 * l) * 512 + lane8;
    bldsE[l] = 16384 + (4 * w + 2 * l) * 512 + lane8;
  }

  f32x4 acc[8][4] = {};

  // prologue: stage tile 0 (Ah,Bh) in deadline order; allow kk1 in flight.
  #pragma unroll
  for (int l = 0; l < 2; ++l) gload16(Bh + (size_t)boffE[l], &lds[bldsE[l]]);
  #pragma unroll
  for (int l = 0; l < 2; ++l) gload16(Ah + (size_t)aoffE[l], &lds[aldsE[l]]);
  #pragma unroll
  for (int l = 0; l < 2; ++l) gload16(Bh + (size_t)(boffE[l] + 32), &lds[bldsE[l] + 512]);
  #pragma unroll
  for (int l = 0; l < 2; ++l) gload16(Ah + (size_t)(aoffE[l] + 32), &lds[aldsE[l] + 512]);
  asm volatile("s_waitcnt vmcnt(4)" ::: "memory");
  __builtin_amdgcn_s_barrier();
  __builtin_amdgcn_sched_barrier(0);

  for (int t = 0; t < NSTEP; ++t){
    const int buf = (t & 1) * 32768;
    const int nbuf = buf ^ 32768;
    const bool pf = (t + 1 < NSTEP);
    int k1 = 0; const short *PA = Ah, *PB = Bh;
    if (pf){
      if (CH == 3){
        const int cc = (t + 1) % 3;
        k1 = ((t + 1) / 3) * 64;
        PA = (cc == 1) ? Al : Ah;
        PB = (cc == 2) ? Bl : Bh;
      } else k1 = (t + 1) * 64;
    }

    s16x8 av[4], bv[4];
    // ---- ph0: quad (m0-3, kk0) ----
    #pragma unroll
    for (int m = 0; m < 4; ++m)
      av[m] = *reinterpret_cast<const s16x8*>(&lds[buf + ((wr * 8 + m) * 2 + 0) * 512 + lane8]);
    #pragma unroll
    for (int n = 0; n < 4; ++n)
      bv[n] = *reinterpret_cast<const s16x8*>(&lds[buf + 16384 + ((wc * 4 + n) * 2 + 0) * 512 + lane8]);
    if (pf){
      #pragma unroll
      for (int l = 0; l < 2; ++l) gload16(PB + (size_t)(boffE[l] + k1), &lds[nbuf + bldsE[l]]);
    }
    __builtin_amdgcn_s_barrier();
    __builtin_amdgcn_s_setprio(1);
    #pragma unroll
    for (int m = 0; m < 4; ++m)
      #pragma unroll
      for (int n = 0; n < 4; ++n)
        acc[m][n] = __builtin_amdgcn_mfma_f32_16x16x32_bf16(av[m], bv[n], acc[m][n], 0, 0, 0);
    __builtin_amdgcn_s_setprio(0);
    __builtin_amdgcn_s_barrier();
    // ---- ph1: quad (m4-7, kk0), bv reused ----
    #pragma unroll
    for (int m = 0; m < 4; ++m)
      av[m] = *reinterpret_cast<const s16x8*>(&lds[buf + ((wr * 8 + 4 + m) * 2 + 0) * 512 + lane8]);
    if (pf){
      #pragma unroll
      for (int l = 0; l < 2; ++l) gload16(PA + (size_t)(aoffE[l] + k1), &lds[nbuf + aldsE[l]]);
    }
    __builtin_amdgcn_s_barrier();
    __builtin_amdgcn_s_setprio(1);
    #pragma unroll
    for (int m = 0; m < 4; ++m)
      #pragma unroll
      for (int n = 0; n < 4; ++n)
        acc[4 + m][n] = __builtin_amdgcn_mfma_f32_16x16x32_bf16(av[m], bv[n], acc[4 + m][n], 0, 0, 0);
    __builtin_amdgcn_s_setprio(0);
    if (pf) asm volatile("s_waitcnt vmcnt(4)" ::: "memory");   // kk1(t) landed; t+1 kk0 in flight
    else    asm volatile("s_waitcnt vmcnt(0)" ::: "memory");   // last tile: drain kk1
    __builtin_amdgcn_s_barrier();
    __builtin_amdgcn_sched_barrier(0);
    // ---- ph2: quad (m0-3, kk1) ----
    #pragma unroll
    for (int m = 0; m < 4; ++m)
      av[m] = *reinterpret_cast<const s16x8*>(&lds[buf + ((wr * 8 + m) * 2 + 1) * 512 + lane8]);
    #pragma unroll
    for (int n = 0; n < 4; ++n)
      bv[n] = *reinterpret_cast<const s16x8*>(&lds[buf + 16384 + ((wc * 4 + n) * 2 + 1) * 512 + lane8]);
    if (pf){
      #pragma unroll
      for (int l = 0; l < 2; ++l) gload16(PB + (size_t)(boffE[l] + k1 + 32), &lds[nbuf + bldsE[l] + 512]);
    }
    __builtin_amdgcn_s_barrier();
    __builtin_amdgcn_s_setprio(1);
    #pragma unroll
    for (int m = 0; m < 4; ++m)
      #pragma unroll
      for (int n = 0; n < 4; ++n)
        acc[m][n] = __builtin_amdgcn_mfma_f32_16x16x32_bf16(av[m], bv[n], acc[m][n], 0, 0, 0);
    __builtin_amdgcn_s_setprio(0);
    __builtin_amdgcn_s_barrier();
    // ---- ph3: quad (m4-7, kk1), bv reused ----
    #pragma unroll
    for (int m = 0; m < 4; ++m)
      av[m] = *reinterpret_cast<const s16x8*>(&lds[buf + ((wr * 8 + 4 + m) * 2 + 1) * 512 + lane8]);
    if (pf){
      #pragma unroll
      for (int l = 0; l < 2; ++l) gload16(PA + (size_t)(aoffE[l] + k1 + 32), &lds[nbuf + aldsE[l] + 512]);
    }
    __builtin_amdgcn_s_barrier();
    __builtin_amdgcn_s_setprio(1);
    #pragma unroll
    for (int m = 0; m < 4; ++m)
      #pragma unroll
      for (int n = 0; n < 4; ++n)
        acc[4 + m][n] = __builtin_amdgcn_mfma_f32_16x16x32_bf16(av[m], bv[n], acc[4 + m][n], 0, 0, 0);
    __builtin_amdgcn_s_setprio(0);
    if (pf){
      asm volatile("s_waitcnt vmcnt(4)" ::: "memory");   // t+1 kk0 landed; t+1 kk1 in flight
      __builtin_amdgcn_s_barrier();
      __builtin_amdgcn_sched_barrier(0);
    }
  }

  #pragma unroll
  for (int m = 0; m < 8; ++m){
    const int row0 = by * 256 + wr * 128 + m * 16 + kg * 4;
    #pragma unroll
    for (int n = 0; n < 4; ++n){
      const int col = bx * 256 + wc * 64 + n * 16 + cl;
      #pragma unroll
      for (int j = 0; j < 4; ++j){
        const size_t off = ((size_t)(row0 + j) + (size_t)bz * CBO) * 1024 + col;
        if (EPI == 0) C[off] = acc[m][n][j];
        else {
          const float v = acc[m][n][j];
          const short hh = f2bf(v);
          Ch[off] = hh; Cl[off] = f2bf(v - bf2f(hh));
        }
      }
    }
  }
}

// K3: in-place row softmax of (logits + mask[b][s]); optional bf16 copy for K4
__global__ __launch_bounds__(256) void k3_softmax(float* __restrict__ logits,
                                                  const float* __restrict__ mask,
                                                  short* __restrict__ sbf){
  const int row = blockIdx.x;       // b*TQ + t
  const int b = row >> 10;
  const int tid = threadIdx.x;
  float* p = logits + (size_t)row * DIM;
  f32x4 v  = *reinterpret_cast<const f32x4*>(p + tid * 4);
  f32x4 mk = *reinterpret_cast<const f32x4*>(mask + (size_t)b * DIM + tid * 4);
  v = v + mk;
  float mx = fmaxf(fmaxf(v[0], v[1]), fmaxf(v[2], v[3]));
  #pragma unroll
  for (int off = 32; off; off >>= 1) mx = fmaxf(mx, __shfl_xor(mx, off));
  __shared__ float red[8];
  const int lane = tid & 63, wid = tid >> 6;
  if (lane == 0) red[wid] = mx;
  __syncthreads();
  mx = fmaxf(fmaxf(red[0], red[1]), fmaxf(red[2], red[3]));
  f32x4 e;
  #pragma unroll
  for (int j = 0; j < 4; ++j) e[j] = __expf(v[j] - mx);
  float s = e[0] + e[1] + e[2] + e[3];
  #pragma unroll
  for (int off = 32; off; off >>= 1) s += __shfl_xor(s, off);
  if (lane == 0) red[4 + wid] = s;
  __syncthreads();
  s = red[4] + red[5] + red[6] + red[7];
  const float inv = 1.0f / s;
  f32x4 o;
  s16x4 ob;
  #pragma unroll
  for (int j = 0; j < 4; ++j){ o[j] = e[j] * inv; ob[j] = f2bf(o[j]); }
  *reinterpret_cast<f32x4*>(p + tid * 4) = o;
  if (sbf) *reinterpret_cast<s16x4*>(sbf + (size_t)row * DIM + tid * 4) = ob;
}

// ---------------- fallback (round-3 passing) kernels ----------------

__global__ __launch_bounds__(256) void k1_qp(const float* __restrict__ A,
                                             const float* __restrict__ Wm,
                                             float* __restrict__ C){
  __shared__ __align__(16) short Ah[BM * STR];
  __shared__ __align__(16) short Al[BM * STR];
  __shared__ __align__(16) short Bh[BN * STR];
  __shared__ __align__(16) short Bl[BN * STR];
  const int tid = threadIdx.x;
  const int m0 = blockIdx.y * BM, n0 = blockIdx.x * BN;
  const int lane = tid & 63, wid = tid >> 6;
  const int wm = (wid >> 1) * 64, wn = (wid & 1) * 64;
  const int cl = lane & 15, kg = lane >> 4;
  const int rr = tid >> 3, f4 = (tid & 7) * 4;
  f32x4 acc[4][4] = {};
  for (int k0 = 0; k0 < DIM; k0 += BK){
    #pragma unroll
    for (int i = 0; i < 4; ++i){
      const int r = rr + i * 32;
      f32x4 va = *reinterpret_cast<const f32x4*>(A  + (size_t)(m0 + r) * DIM + k0 + f4);
      f32x4 vb = *reinterpret_cast<const f32x4*>(Wm + (size_t)(n0 + r) * DIM + k0 + f4);
      s16x4 ha, la, hb, lb;
      #pragma unroll
      for (int j = 0; j < 4; ++j){
        ha[j] = f2bf(va[j]); la[j] = f2bf(va[j] - bf2f(ha[j]));
        hb[j] = f2bf(vb[j]); lb[j] = f2bf(vb[j] - bf2f(hb[j]));
      }
      *reinterpret_cast<s16x4*>(&Ah[r * STR + f4]) = ha;
      *reinterpret_cast<s16x4*>(&Al[r * STR + f4]) = la;
      *reinterpret_cast<s16x4*>(&Bh[r * STR + f4]) = hb;
      *reinterpret_cast<s16x4*>(&Bl[r * STR + f4]) = lb;
    }
    __syncthreads();
    s16x8 ah[4], al8[4], bh8[4], bl8[4];
    #pragma unroll
    for (int m = 0; m < 4; ++m){
      ah[m]  = *reinterpret_cast<const s16x8*>(&Ah[(wm + m * 16 + cl) * STR + kg * 8]);
      al8[m] = *reinterpret_cast<const s16x8*>(&Al[(wm + m * 16 + cl) * STR + kg * 8]);
    }
    #pragma unroll
    for (int n = 0; n < 4; ++n){
      bh8[n] = *reinterpret_cast<const s16x8*>(&Bh[(wn + n * 16 + cl) * STR + kg * 8]);
      bl8[n] = *reinterpret_cast<const s16x8*>(&Bl[(wn + n * 16 + cl) * STR + kg * 8]);
    }
    #pragma unroll
    for (int m = 0; m < 4; ++m)
      #pragma unroll
      for (int n = 0; n < 4; ++n){
        acc[m][n] = __builtin_amdgcn_mfma_f32_16x16x32_bf16(ah[m],  bh8[n], acc[m][n], 0, 0, 0);
        acc[m][n] = __builtin_amdgcn_mfma_f32_16x16x32_bf16(al8[m], bh8[n], acc[m][n], 0, 0, 0);
        acc[m][n] = __builtin_amdgcn_mfma_f32_16x16x32_bf16(ah[m],  bl8[n], acc[m][n], 0, 0, 0);
      }
    __syncthreads();
  }
  #pragma unroll
  for (int m = 0; m < 4; ++m){
    const int row = m0 + wm + m * 16 + kg * 4;
    #pragma unroll
    for (int n = 0; n < 4; ++n){
      const int col = n0 + wn + n * 16 + cl;
      #pragma unroll
      for (int j = 0; j < 4; ++j)
        C[(size_t)(row + j) * DIM + col] = acc[m][n][j];
    }
  }
}

__global__ __launch_bounds__(256) void k2_logits(const float* __restrict__ qp,
                                                 const float* __restrict__ keys,
                                                 float* __restrict__ out){
  __shared__ __align__(16) short Ah[BM * STR];
  __shared__ __align__(16) short Al[BM * STR];
  __shared__ __align__(16) short Bh[BN * STR];
  __shared__ __align__(16) short Bl[BN * STR];
  const int tid = threadIdx.x;
  const int b = blockIdx.z;
  const int t0 = blockIdx.y * BM, s0 = blockIdx.x * BN;
  const int lane = tid & 63, wid = tid >> 6;
  const int wm = (wid >> 1) * 64, wn = (wid & 1) * 64;
  const int cl = lane & 15, kg = lane >> 4;
  const int rr = tid >> 3, f4 = (tid & 7) * 4;
  f32x4 acc[4][4] = {};
  for (int k0 = 0; k0 < DIM; k0 += BK){
    #pragma unroll
    for (int i = 0; i < 4; ++i){
      const int r = rr + i * 32;
      f32x4 va = *reinterpret_cast<const f32x4*>(qp   + (size_t)((t0 + r) * NB + b) * DIM + k0 + f4);
      f32x4 vb = *reinterpret_cast<const f32x4*>(keys + ((size_t)b * DIM + s0 + r) * DIM + k0 + f4);
      s16x4 ha, la, hb, lb;
      #pragma unroll
      for (int j = 0; j < 4; ++j){
        ha[j] = f2bf(va[j]); la[j] = f2bf(va[j] - bf2f(ha[j]));
        hb[j] = f2bf(vb[j]); lb[j] = f2bf(vb[j] - bf2f(hb[j]));
      }
      *reinterpret_cast<s16x4*>(&Ah[r * STR + f4]) = ha;
      *reinterpret_cast<s16x4*>(&Al[r * STR + f4]) = la;
      *reinterpret_cast<s16x4*>(&Bh[r * STR + f4]) = hb;
      *reinterpret_cast<s16x4*>(&Bl[r * STR + f4]) = lb;
    }
    __syncthreads();
    s16x8 ah[4], al8[4], bh8[4], bl8[4];
    #pragma unroll
    for (int m = 0; m < 4; ++m){
      ah[m]  = *reinterpret_cast<const s16x8*>(&Ah[(wm + m * 16 + cl) * STR + kg * 8]);
      al8[m] = *reinterpret_cast<const s16x8*>(&Al[(wm + m * 16 + cl) * STR + kg * 8]);
    }
    #pragma unroll
    for (int n = 0; n < 4; ++n){
      bh8[n] = *reinterpret_cast<const s16x8*>(&Bh[(wn + n * 16 + cl) * STR + kg * 8]);
      bl8[n] = *reinterpret_cast<const s16x8*>(&Bl[(wn + n * 16 + cl) * STR + kg * 8]);
    }
    #pragma unroll
    for (int m = 0; m < 4; ++m)
      #pragma unroll
      for (int n = 0; n < 4; ++n){
        acc[m][n] = __builtin_amdgcn_mfma_f32_16x16x32_bf16(ah[m],  bh8[n], acc[m][n], 0, 0, 0);
        acc[m][n] = __builtin_amdgcn_mfma_f32_16x16x32_bf16(al8[m], bh8[n], acc[m][n], 0, 0, 0);
        acc[m][n] = __builtin_amdgcn_mfma_f32_16x16x32_bf16(ah[m],  bl8[n], acc[m][n], 0, 0, 0);
      }
    __syncthreads();
  }
  #pragma unroll
  for (int m = 0; m < 4; ++m){
    const int trow = t0 + wm + m * 16 + kg * 4;
    #pragma unroll
    for (int n = 0; n < 4; ++n){
      const int scol = s0 + wn + n * 16 + cl;
      #pragma unroll
      for (int j = 0; j < 4; ++j)
        out[((size_t)b * TQn + trow + j) * DIM + scol] = acc[m][n][j];
    }
  }
}

__global__ __launch_bounds__(256) void k4_ctx(const float* __restrict__ score,
                                              const float* __restrict__ values,
                                              float* __restrict__ ctx){
  __shared__ __align__(16) short As[BM * STR];
  __shared__ __align__(16) float Vs[BK * VSTR];
  const int tid = threadIdx.x;
  const int b = blockIdx.z;
  const int t0 = blockIdx.y * BM, v0 = blockIdx.x * BN;
  const int lane = tid & 63, wid = tid >> 6;
  const int wm = (wid >> 1) * 64, wn = (wid & 1) * 64;
  const int cl = lane & 15, kg = lane >> 4;
  const int rr = tid >> 3, f4 = (tid & 7) * 4;
  const int vr = tid >> 5, vc = tid & 31;
  f32x4 acc[4][4] = {};
  for (int k0 = 0; k0 < DIM; k0 += BK){
    #pragma unroll
    for (int i = 0; i < 4; ++i){
      const int r = rr + i * 32;
      f32x4 va = *reinterpret_cast<const f32x4*>(score + ((size_t)b * TQn + t0 + r) * DIM + k0 + f4);
      s16x4 ha;
      #pragma unroll
      for (int j = 0; j < 4; ++j) ha[j] = f2bf(va[j]);
      *reinterpret_cast<s16x4*>(&As[r * STR + f4]) = ha;
      const int vrow = vr + i * 8;
      f32x4 vv = *reinterpret_cast<const f32x4*>(values + ((size_t)b * DIM + k0 + vrow) * DIM + v0 + vc * 4);
      const int cb = vc ^ (((vrow >> 3) & 1) << 2);
      *reinterpret_cast<f32x4*>(&Vs[vrow * VSTR + cb * 4]) = vv;
    }
    __syncthreads();
    s16x8 af[4], bfr[4];
    #pragma unroll
    for (int m = 0; m < 4; ++m)
      af[m] = *reinterpret_cast<const s16x8*>(&As[(wm + m * 16 + cl) * STR + kg * 8]);
    #pragma unroll
    for (int n = 0; n < 4; ++n){
      const int colb = wn + n * 16 + cl;
      const int cb = (colb >> 2) ^ ((kg & 1) << 2);
      #pragma unroll
      for (int j = 0; j < 8; ++j){
        const int rowv = kg * 8 + j;
        bfr[n][j] = f2bf(Vs[rowv * VSTR + cb * 4 + (colb & 3)]);
      }
    }
    #pragma unroll
    for (int m = 0; m < 4; ++m)
      #pragma unroll
      for (int n = 0; n < 4; ++n)
        acc[m][n] = __builtin_amdgcn_mfma_f32_16x16x32_bf16(af[m], bfr[n], acc[m][n], 0, 0, 0);
    __syncthreads();
  }
  #pragma unroll
  for (int m = 0; m < 4; ++m){
    const int trow = t0 + wm + m * 16 + kg * 4;
    #pragma unroll
    for (int n = 0; n < 4; ++n){
      const int vcol = v0 + wn + n * 16 + cl;
      #pragma unroll
      for (int j = 0; j < 4; ++j)
        ctx[((size_t)b * TQn + trow + j) * DIM + vcol] = acc[m][n][j];
    }
  }
}

extern "C" void kernel_launch(void* const* d_in, const int* in_sizes, int n_in,
                              void* d_out, int out_size, void* d_ws, size_t ws_size,
                              hipStream_t stream){
  (void)in_sizes; (void)n_in; (void)out_size;
  const float* query  = (const float*)d_in[0];  // [1024][16][1024] == m-major [16384][1024]
  const float* keys   = (const float*)d_in[1];  // [16][1024][1024]
  const float* values = (const float*)d_in[2];  // [16][1024][1024]
  const float* mask   = (const float*)d_in[3];  // [16][1024]
  const float* Wm     = (const float*)d_in[4];  // [1024][1024]
  float* score = (float*)d_out;                              // [16][1024][1024]
  float* ctx   = score + (size_t)NB * TQn * DIM;             // qp-plane scratch then real ctx
  dim3 blk(256, 1, 1);
  dim3 blk512(512, 1, 1);

  const size_t M16 = (size_t)16 * 1024 * 1024;   // 16M shorts
  const size_t M1  = (size_t)1024 * 1024;
  const size_t need = (4 * M16 + 2 * M1 + 2 * M16) * 2;   // 196 MB
  if (ws_size >= need){
    short* w  = (short*)d_ws;
    short* qh = w;                 // query hi
    short* ql = qh + M16;
    short* kh = ql + M16;          // keys hi
    short* kl = kh + M16;
    short* wh = kl + M16;          // W hi
    short* wl = wh + M1;
    short* vT = wl + M1;           // values^T bf16 [b][v][s]
    short* sb = vT + M16;          // score bf16
    short* qph = (short*)ctx;      // qp hi plane (m-major [16384][1024])
    short* qpl = qph + M16;

    k0_split<<<dim3(16384, 1, 1), blk, 0, stream>>>(query, qh, ql);
    k0_split<<<dim3(16384, 1, 1), blk, 0, stream>>>(keys, kh, kl);
    k0_split<<<dim3(1024, 1, 1), blk, 0, stream>>>(Wm, wh, wl);
    k0_vtrans<<<dim3(16, 16, 16), blk, 0, stream>>>(values, vT);
    // K1: qp = query . W^T -> bf16 hi/lo planes (M=16384, N=1024)
    gemm256<3, 1><<<dim3(4, 64, 1), blk512, 0, stream>>>(qh, ql, wh, wl,
        nullptr, qph, qpl, 1, 0, 1, 0, 0);
    // K2: logits[b][t][s] = qp[t*16+b][:] . keys[b][s][:]
    gemm256<3, 0><<<dim3(4, 4, 16), blk512, 0, stream>>>(qph, qpl, kh, kl,
        score, nullptr, nullptr, 16, 1, 1, 1024, 1024);
    k3_softmax<<<dim3(NB * TQn, 1, 1), blk, 0, stream>>>(score, mask, sb);
    // K4: ctx[b][t][v] = score[b][t][:] . vT[b][v][:]
    gemm256<1, 0><<<dim3(4, 4, 16), blk512, 0, stream>>>(sb, nullptr, vT, nullptr,
        ctx, nullptr, nullptr, 1, 1024, 1, 1024, 1024);
  } else {
    k1_qp<<<dim3(DIM / BN, (TQn * NB) / BM, 1), blk, 0, stream>>>(query, Wm, ctx);
    k2_logits<<<dim3(DIM / BN, TQn / BM, NB), blk, 0, stream>>>(ctx, keys, score);
    k3_softmax<<<dim3(NB * TQn, 1, 1), blk, 0, stream>>>(score, mask, nullptr);
    k4_ctx<<<dim3(DIM / BN, TQn / BM, NB), blk, 0, stream>>>(score, values, ctx);
  }
}

// Round 9
// 332.873 us; speedup vs baseline: 1.2428x; 1.1110x over previous
//
#include <hip/hip_runtime.h>
#include <hip/hip_bf16.h>

#define TQn 1024
#define NB  16
#define DIM 1024
#define BM  128
#define BN  128
#define BK  32
#define STR 40
#define VSTR 132

typedef __attribute__((ext_vector_type(4))) float f32x4;
typedef __attribute__((ext_vector_type(8))) short s16x8;
typedef __attribute__((ext_vector_type(4))) short s16x4;
typedef __attribute__((ext_vector_type(8))) _Float16 h16x8;

__device__ __forceinline__ short f2bf(float f){
  union { float f; unsigned u; } v; v.f = f;
  unsigned r = v.u + 0x7fffu + ((v.u >> 16) & 1u);  // RNE
  return (short)(r >> 16);
}
__device__ __forceinline__ float bf2f(short h){
  union { unsigned u; float f; } v; v.u = ((unsigned)(unsigned short)h) << 16;
  return v.f;
}

__device__ __forceinline__ void gload16(const short* g, short* l){
#if __has_builtin(__builtin_amdgcn_global_load_lds)
  __builtin_amdgcn_global_load_lds(
      (const __attribute__((address_space(1))) unsigned int*)(const void*)g,
      (__attribute__((address_space(3))) unsigned int*)(void*)l, 16, 0, 0);
#else
  *reinterpret_cast<s16x8*>(l) = *reinterpret_cast<const s16x8*>(g);
#endif
}

// CH=2 path uses fp16 MFMA; others bf16. Same fragment geometry (8 elems, 4 VGPRs).
template<int CH>
__device__ __forceinline__ f32x4 mfma_frag(s16x8 a, s16x8 b, f32x4 c){
  if constexpr (CH == 2)
    return __builtin_amdgcn_mfma_f32_16x16x32_f16(
        __builtin_bit_cast(h16x8, a), __builtin_bit_cast(h16x8, b), c, 0, 0, 0);
  else
    return __builtin_amdgcn_mfma_f32_16x16x32_bf16(a, b, c, 0, 0, 0);
}

// ---------------- fast path ----------------

// fp32 -> bf16 hi/lo planes
__global__ __launch_bounds__(256) void k0_split(const float* __restrict__ in,
                                                short* __restrict__ hi,
                                                short* __restrict__ lo){
  const size_t i = ((size_t)blockIdx.x * 256 + threadIdx.x) * 4;
  f32x4 v = *reinterpret_cast<const f32x4*>(in + i);
  s16x4 h, l;
  #pragma unroll
  for (int j = 0; j < 4; ++j){ h[j] = f2bf(v[j]); l[j] = f2bf(v[j] - bf2f(h[j])); }
  *reinterpret_cast<s16x4*>(hi + i) = h;
  *reinterpret_cast<s16x4*>(lo + i) = l;
}

// fp32 -> single fp16 plane (for keys; error 2^-11 rel -> logit err ~0.009)
__global__ __launch_bounds__(256) void k0_cvt16(const float* __restrict__ in,
                                                short* __restrict__ out){
  const size_t i = ((size_t)blockIdx.x * 256 + threadIdx.x) * 4;
  f32x4 v = *reinterpret_cast<const f32x4*>(in + i);
  s16x4 o;
  #pragma unroll
  for (int j = 0; j < 4; ++j){
    _Float16 h = (_Float16)v[j];
    o[j] = __builtin_bit_cast(short, h);
  }
  *reinterpret_cast<s16x4*>(out + i) = o;
}

// values [b][s][v] fp32 -> vT [b][v][s] bf16
__global__ __launch_bounds__(256) void k0_vtrans(const float* __restrict__ vals,
                                                 short* __restrict__ vT){
  __shared__ short T[64 * 72];
  const int t = threadIdx.x;
  const int v0 = blockIdx.x * 64, s0 = blockIdx.y * 64, b = blockIdx.z;
  const int r16 = t >> 4, c4 = (t & 15) * 4;
  #pragma unroll
  for (int i = 0; i < 4; ++i){
    const int sl = i * 16 + r16;
    f32x4 v = *reinterpret_cast<const f32x4*>(vals + ((size_t)b * TQn + s0 + sl) * DIM + v0 + c4);
    #pragma unroll
    for (int j = 0; j < 4; ++j) T[(c4 + j) * 72 + sl] = f2bf(v[j]);
  }
  __syncthreads();
  #pragma unroll
  for (int i = 0; i < 4; ++i){
    const int vl = i * 16 + r16;
    s16x4 o = *reinterpret_cast<const s16x4*>(&T[vl * 72 + c4]);
    *reinterpret_cast<s16x4*>(vT + ((size_t)b * DIM + v0 + vl) * TQn + s0 + c4) = o;
  }
}

// 256x256 A*B^T GEMM, 8 waves (2Mx4N), BK=64, dbuf 128KB, fragment-major
// (conflict-free b128), counted-vmcnt pipeline (round-8 proven structure).
// CH=3: bf16 virtual-K 3x1024 (Ah*Bh + Al*Bh + Ah*Bl)
// CH=2: fp16 virtual-K 2x1024 (Ah*B + Al*B), B single plane
// CH=1: bf16 plain 1024
// EPI: 0 = fp32 C; 1 = bf16 hi/lo planes; 2 = fp16 hi/lo planes
template<int CH, int EPI>
__global__ __launch_bounds__(512, 2) void gemm256(
    const short* __restrict__ Ah, const short* __restrict__ Al,
    const short* __restrict__ Bh, const short* __restrict__ Bl,
    float* __restrict__ C, short* __restrict__ Ch, short* __restrict__ Cl,
    int ARS, int ABO, int BRS, int BBO, int CBO)
{
  constexpr int NSTEP = (CH == 3) ? 48 : (CH == 2) ? 32 : 16;
  __shared__ __align__(16) short lds[2 * 32768];   // 128 KB
  const int tid = threadIdx.x;
  const int lane = tid & 63, w = tid >> 6;
  const int cl = lane & 15, kg = lane >> 4;
  const int lane8 = lane * 8;
  const int bx = blockIdx.x, by = blockIdx.y, bz = blockIdx.z;
  const int wr = w >> 2, wc = w & 3;

  int aoffE[2], boffE[2], aldsE[2], bldsE[2];
  #pragma unroll
  for (int l = 0; l < 2; ++l){
    const int rg = 2 * w + l;
    const int arow = by * 256 + rg * 16 + cl;
    const int brow = bx * 256 + rg * 16 + cl;
    aoffE[l] = (arow * ARS + bz * ABO) * 1024 + kg * 8;
    boffE[l] = (brow * BRS + bz * BBO) * 1024 + kg * 8;
    aldsE[l] = (4 * w + 2 * l) * 512 + lane8;
    bldsE[l] = 16384 + (4 * w + 2 * l) * 512 + lane8;
  }

  f32x4 acc[8][4] = {};

  // prologue: stage tile 0 (chain 0 -> Ah,Bh) in deadline order; kk1 stays in flight.
  #pragma unroll
  for (int l = 0; l < 2; ++l) gload16(Bh + (size_t)boffE[l], &lds[bldsE[l]]);
  #pragma unroll
  for (int l = 0; l < 2; ++l) gload16(Ah + (size_t)aoffE[l], &lds[aldsE[l]]);
  #pragma unroll
  for (int l = 0; l < 2; ++l) gload16(Bh + (size_t)(boffE[l] + 32), &lds[bldsE[l] + 512]);
  #pragma unroll
  for (int l = 0; l < 2; ++l) gload16(Ah + (size_t)(aoffE[l] + 32), &lds[aldsE[l] + 512]);
  asm volatile("s_waitcnt vmcnt(4)" ::: "memory");
  __builtin_amdgcn_s_barrier();
  __builtin_amdgcn_sched_barrier(0);

  for (int t = 0; t < NSTEP; ++t){
    const int buf = (t & 1) * 32768;
    const int nbuf = buf ^ 32768;
    const bool pf = (t + 1 < NSTEP);
    int k1 = 0; const short *PA = Ah, *PB = Bh;
    if (pf){
      if (CH == 3){
        const int cc = (t + 1) % 3;
        k1 = ((t + 1) / 3) * 64;
        PA = (cc == 1) ? Al : Ah;
        PB = (cc == 2) ? Bl : Bh;
      } else if (CH == 2){
        k1 = ((t + 1) >> 1) * 64;
        PA = ((t + 1) & 1) ? Al : Ah;
        PB = Bh;
      } else k1 = (t + 1) * 64;
    }

    s16x8 av[4], bv[4];
    // ---- ph0: quad (m0-3, kk0) ----
    #pragma unroll
    for (int m = 0; m < 4; ++m)
      av[m] = *reinterpret_cast<const s16x8*>(&lds[buf + ((wr * 8 + m) * 2 + 0) * 512 + lane8]);
    #pragma unroll
    for (int n = 0; n < 4; ++n)
      bv[n] = *reinterpret_cast<const s16x8*>(&lds[buf + 16384 + ((wc * 4 + n) * 2 + 0) * 512 + lane8]);
    if (pf){
      #pragma unroll
      for (int l = 0; l < 2; ++l) gload16(PB + (size_t)(boffE[l] + k1), &lds[nbuf + bldsE[l]]);
    }
    __builtin_amdgcn_s_barrier();
    __builtin_amdgcn_s_setprio(1);
    #pragma unroll
    for (int m = 0; m < 4; ++m)
      #pragma unroll
      for (int n = 0; n < 4; ++n)
        acc[m][n] = mfma_frag<CH>(av[m], bv[n], acc[m][n]);
    __builtin_amdgcn_s_setprio(0);
    __builtin_amdgcn_s_barrier();
    // ---- ph1: quad (m4-7, kk0), bv reused ----
    #pragma unroll
    for (int m = 0; m < 4; ++m)
      av[m] = *reinterpret_cast<const s16x8*>(&lds[buf + ((wr * 8 + 4 + m) * 2 + 0) * 512 + lane8]);
    if (pf){
      #pragma unroll
      for (int l = 0; l < 2; ++l) gload16(PA + (size_t)(aoffE[l] + k1), &lds[nbuf + aldsE[l]]);
    }
    __builtin_amdgcn_s_barrier();
    __builtin_amdgcn_s_setprio(1);
    #pragma unroll
    for (int m = 0; m < 4; ++m)
      #pragma unroll
      for (int n = 0; n < 4; ++n)
        acc[4 + m][n] = mfma_frag<CH>(av[m], bv[n], acc[4 + m][n]);
    __builtin_amdgcn_s_setprio(0);
    if (pf) asm volatile("s_waitcnt vmcnt(4)" ::: "memory");
    else    asm volatile("s_waitcnt vmcnt(0)" ::: "memory");
    __builtin_amdgcn_s_barrier();
    __builtin_amdgcn_sched_barrier(0);
    // ---- ph2: quad (m0-3, kk1) ----
    #pragma unroll
    for (int m = 0; m < 4; ++m)
      av[m] = *reinterpret_cast<const s16x8*>(&lds[buf + ((wr * 8 + m) * 2 + 1) * 512 + lane8]);
    #pragma unroll
    for (int n = 0; n < 4; ++n)
      bv[n] = *reinterpret_cast<const s16x8*>(&lds[buf + 16384 + ((wc * 4 + n) * 2 + 1) * 512 + lane8]);
    if (pf){
      #pragma unroll
      for (int l = 0; l < 2; ++l) gload16(PB + (size_t)(boffE[l] + k1 + 32), &lds[nbuf + bldsE[l] + 512]);
    }
    __builtin_amdgcn_s_barrier();
    __builtin_amdgcn_s_setprio(1);
    #pragma unroll
    for (int m = 0; m < 4; ++m)
      #pragma unroll
      for (int n = 0; n < 4; ++n)
        acc[m][n] = mfma_frag<CH>(av[m], bv[n], acc[m][n]);
    __builtin_amdgcn_s_setprio(0);
    __builtin_amdgcn_s_barrier();
    // ---- ph3: quad (m4-7, kk1), bv reused ----
    #pragma unroll
    for (int m = 0; m < 4; ++m)
      av[m] = *reinterpret_cast<const s16x8*>(&lds[buf + ((wr * 8 + 4 + m) * 2 + 1) * 512 + lane8]);
    if (pf){
      #pragma unroll
      for (int l = 0; l < 2; ++l) gload16(PA + (size_t)(aoffE[l] + k1 + 32), &lds[nbuf + aldsE[l] + 512]);
    }
    __builtin_amdgcn_s_barrier();
    __builtin_amdgcn_s_setprio(1);
    #pragma unroll
    for (int m = 0; m < 4; ++m)
      #pragma unroll
      for (int n = 0; n < 4; ++n)
        acc[4 + m][n] = mfma_frag<CH>(av[m], bv[n], acc[4 + m][n]);
    __builtin_amdgcn_s_setprio(0);
    if (pf){
      asm volatile("s_waitcnt vmcnt(4)" ::: "memory");
      __builtin_amdgcn_s_barrier();
      __builtin_amdgcn_sched_barrier(0);
    }
  }

  #pragma unroll
  for (int m = 0; m < 8; ++m){
    const int row0 = by * 256 + wr * 128 + m * 16 + kg * 4;
    #pragma unroll
    for (int n = 0; n < 4; ++n){
      const int col = bx * 256 + wc * 64 + n * 16 + cl;
      #pragma unroll
      for (int j = 0; j < 4; ++j){
        const size_t off = ((size_t)(row0 + j) + (size_t)bz * CBO) * 1024 + col;
        if (EPI == 0) C[off] = acc[m][n][j];
        else if (EPI == 1){
          const float v = acc[m][n][j];
          const short hh = f2bf(v);
          Ch[off] = hh; Cl[off] = f2bf(v - bf2f(hh));
        } else {
          const float v = acc[m][n][j];
          const _Float16 hh = (_Float16)v;
          Ch[off] = __builtin_bit_cast(short, hh);
          const _Float16 ll = (_Float16)(v - (float)hh);
          Cl[off] = __builtin_bit_cast(short, ll);
        }
      }
    }
  }
}

// K3: in-place row softmax of (logits + mask[b][s]); optional bf16 copy for K4
__global__ __launch_bounds__(256) void k3_softmax(float* __restrict__ logits,
                                                  const float* __restrict__ mask,
                                                  short* __restrict__ sbf){
  const int row = blockIdx.x;       // b*TQ + t
  const int b = row >> 10;
  const int tid = threadIdx.x;
  float* p = logits + (size_t)row * DIM;
  f32x4 v  = *reinterpret_cast<const f32x4*>(p + tid * 4);
  f32x4 mk = *reinterpret_cast<const f32x4*>(mask + (size_t)b * DIM + tid * 4);
  v = v + mk;
  float mx = fmaxf(fmaxf(v[0], v[1]), fmaxf(v[2], v[3]));
  #pragma unroll
  for (int off = 32; off; off >>= 1) mx = fmaxf(mx, __shfl_xor(mx, off));
  __shared__ float red[8];
  const int lane = tid & 63, wid = tid >> 6;
  if (lane == 0) red[wid] = mx;
  __syncthreads();
  mx = fmaxf(fmaxf(red[0], red[1]), fmaxf(red[2], red[3]));
  f32x4 e;
  #pragma unroll
  for (int j = 0; j < 4; ++j) e[j] = __expf(v[j] - mx);
  float s = e[0] + e[1] + e[2] + e[3];
  #pragma unroll
  for (int off = 32; off; off >>= 1) s += __shfl_xor(s, off);
  if (lane == 0) red[4 + wid] = s;
  __syncthreads();
  s = red[4] + red[5] + red[6] + red[7];
  const float inv = 1.0f / s;
  f32x4 o;
  s16x4 ob;
  #pragma unroll
  for (int j = 0; j < 4; ++j){ o[j] = e[j] * inv; ob[j] = f2bf(o[j]); }
  *reinterpret_cast<f32x4*>(p + tid * 4) = o;
  if (sbf) *reinterpret_cast<s16x4*>(sbf + (size_t)row * DIM + tid * 4) = ob;
}

// ---------------- fallback (round-3 passing) kernels ----------------

__global__ __launch_bounds__(256) void k1_qp(const float* __restrict__ A,
                                             const float* __restrict__ Wm,
                                             float* __restrict__ C){
  __shared__ __align__(16) short Ah[BM * STR];
  __shared__ __align__(16) short Al[BM * STR];
  __shared__ __align__(16) short Bh[BN * STR];
  __shared__ __align__(16) short Bl[BN * STR];
  const int tid = threadIdx.x;
  const int m0 = blockIdx.y * BM, n0 = blockIdx.x * BN;
  const int lane = tid & 63, wid = tid >> 6;
  const int wm = (wid >> 1) * 64, wn = (wid & 1) * 64;
  const int cl = lane & 15, kg = lane >> 4;
  const int rr = tid >> 3, f4 = (tid & 7) * 4;
  f32x4 acc[4][4] = {};
  for (int k0 = 0; k0 < DIM; k0 += BK){
    #pragma unroll
    for (int i = 0; i < 4; ++i){
      const int r = rr + i * 32;
      f32x4 va = *reinterpret_cast<const f32x4*>(A  + (size_t)(m0 + r) * DIM + k0 + f4);
      f32x4 vb = *reinterpret_cast<const f32x4*>(Wm + (size_t)(n0 + r) * DIM + k0 + f4);
      s16x4 ha, la, hb, lb;
      #pragma unroll
      for (int j = 0; j < 4; ++j){
        ha[j] = f2bf(va[j]); la[j] = f2bf(va[j] - bf2f(ha[j]));
        hb[j] = f2bf(vb[j]); lb[j] = f2bf(vb[j] - bf2f(hb[j]));
      }
      *reinterpret_cast<s16x4*>(&Ah[r * STR + f4]) = ha;
      *reinterpret_cast<s16x4*>(&Al[r * STR + f4]) = la;
      *reinterpret_cast<s16x4*>(&Bh[r * STR + f4]) = hb;
      *reinterpret_cast<s16x4*>(&Bl[r * STR + f4]) = lb;
    }
    __syncthreads();
    s16x8 ah[4], al8[4], bh8[4], bl8[4];
    #pragma unroll
    for (int m = 0; m < 4; ++m){
      ah[m]  = *reinterpret_cast<const s16x8*>(&Ah[(wm + m * 16 + cl) * STR + kg * 8]);
      al8[m] = *reinterpret_cast<const s16x8*>(&Al[(wm + m * 16 + cl) * STR + kg * 8]);
    }
    #pragma unroll
    for (int n = 0; n < 4; ++n){
      bh8[n] = *reinterpret_cast<const s16x8*>(&Bh[(wn + n * 16 + cl) * STR + kg * 8]);
      bl8[n] = *reinterpret_cast<const s16x8*>(&Bl[(wn + n * 16 + cl) * STR + kg * 8]);
    }
    #pragma unroll
    for (int m = 0; m < 4; ++m)
      #pragma unroll
      for (int n = 0; n < 4; ++n){
        acc[m][n] = __builtin_amdgcn_mfma_f32_16x16x32_bf16(ah[m],  bh8[n], acc[m][n], 0, 0, 0);
        acc[m][n] = __builtin_amdgcn_mfma_f32_16x16x32_bf16(al8[m], bh8[n], acc[m][n], 0, 0, 0);
        acc[m][n] = __builtin_amdgcn_mfma_f32_16x16x32_bf16(ah[m],  bl8[n], acc[m][n], 0, 0, 0);
      }
    __syncthreads();
  }
  #pragma unroll
  for (int m = 0; m < 4; ++m){
    const int row = m0 + wm + m * 16 + kg * 4;
    #pragma unroll
    for (int n = 0; n < 4; ++n){
      const int col = n0 + wn + n * 16 + cl;
      #pragma unroll
      for (int j = 0; j < 4; ++j)
        C[(size_t)(row + j) * DIM + col] = acc[m][n][j];
    }
  }
}

__global__ __launch_bounds__(256) void k2_logits(const float* __restrict__ qp,
                                                 const float* __restrict__ keys,
                                                 float* __restrict__ out){
  __shared__ __align__(16) short Ah[BM * STR];
  __shared__ __align__(16) short Al[BM * STR];
  __shared__ __align__(16) short Bh[BN * STR];
  __shared__ __align__(16) short Bl[BN * STR];
  const int tid = threadIdx.x;
  const int b = blockIdx.z;
  const int t0 = blockIdx.y * BM, s0 = blockIdx.x * BN;
  const int lane = tid & 63, wid = tid >> 6;
  const int wm = (wid >> 1) * 64, wn = (wid & 1) * 64;
  const int cl = lane & 15, kg = lane >> 4;
  const int rr = tid >> 3, f4 = (tid & 7) * 4;
  f32x4 acc[4][4] = {};
  for (int k0 = 0; k0 < DIM; k0 += BK){
    #pragma unroll
    for (int i = 0; i < 4; ++i){
      const int r = rr + i * 32;
      f32x4 va = *reinterpret_cast<const f32x4*>(qp   + (size_t)((t0 + r) * NB + b) * DIM + k0 + f4);
      f32x4 vb = *reinterpret_cast<const f32x4*>(keys + ((size_t)b * DIM + s0 + r) * DIM + k0 + f4);
      s16x4 ha, la, hb, lb;
      #pragma unroll
      for (int j = 0; j < 4; ++j){
        ha[j] = f2bf(va[j]); la[j] = f2bf(va[j] - bf2f(ha[j]));
        hb[j] = f2bf(vb[j]); lb[j] = f2bf(vb[j] - bf2f(hb[j]));
      }
      *reinterpret_cast<s16x4*>(&Ah[r * STR + f4]) = ha;
      *reinterpret_cast<s16x4*>(&Al[r * STR + f4]) = la;
      *reinterpret_cast<s16x4*>(&Bh[r * STR + f4]) = hb;
      *reinterpret_cast<s16x4*>(&Bl[r * STR + f4]) = lb;
    }
    __syncthreads();
    s16x8 ah[4], al8[4], bh8[4], bl8[4];
    #pragma unroll
    for (int m = 0; m < 4; ++m){
      ah[m]  = *reinterpret_cast<const s16x8*>(&Ah[(wm + m * 16 + cl) * STR + kg * 8]);
      al8[m] = *reinterpret_cast<const s16x8*>(&Al[(wm + m * 16 + cl) * STR + kg * 8]);
    }
    #pragma unroll
    for (int n = 0; n < 4; ++n){
      bh8[n] = *reinterpret_cast<const s16x8*>(&Bh[(wn + n * 16 + cl) * STR + kg * 8]);
      bl8[n] = *reinterpret_cast<const s16x8*>(&Bl[(wn + n * 16 + cl) * STR + kg * 8]);
    }
    #pragma unroll
    for (int m = 0; m < 4; ++m)
      #pragma unroll
      for (int n = 0; n < 4; ++n){
        acc[m][n] = __builtin_amdgcn_mfma_f32_16x16x32_bf16(ah[m],  bh8[n], acc[m][n], 0, 0, 0);
        acc[m][n] = __builtin_amdgcn_mfma_f32_16x16x32_bf16(al8[m], bh8[n], acc[m][n], 0, 0, 0);
        acc[m][n] = __builtin_amdgcn_mfma_f32_16x16x32_bf16(ah[m],  bl8[n], acc[m][n], 0, 0, 0);
      }
    __syncthreads();
  }
  #pragma unroll
  for (int m = 0; m < 4; ++m){
    const int trow = t0 + wm + m * 16 + kg * 4;
    #pragma unroll
    for (int n = 0; n < 4; ++n){
      const int scol = s0 + wn + n * 16 + cl;
      #pragma unroll
      for (int j = 0; j < 4; ++j)
        out[((size_t)b * TQn + trow + j) * DIM + scol] = acc[m][n][j];
    }
  }
}

__global__ __launch_bounds__(256) void k4_ctx(const float* __restrict__ score,
                                              const float* __restrict__ values,
                                              float* __restrict__ ctx){
  __shared__ __align__(16) short As[BM * STR];
  __shared__ __align__(16) float Vs[BK * VSTR];
  const int tid = threadIdx.x;
  const int b = blockIdx.z;
  const int t0 = blockIdx.y * BM, v0 = blockIdx.x * BN;
  const int lane = tid & 63, wid = tid >> 6;
  const int wm = (wid >> 1) * 64, wn = (wid & 1) * 64;
  const int cl = lane & 15, kg = lane >> 4;
  const int rr = tid >> 3, f4 = (tid & 7) * 4;
  const int vr = tid >> 5, vc = tid & 31;
  f32x4 acc[4][4] = {};
  for (int k0 = 0; k0 < DIM; k0 += BK){
    #pragma unroll
    for (int i = 0; i < 4; ++i){
      const int r = rr + i * 32;
      f32x4 va = *reinterpret_cast<const f32x4*>(score + ((size_t)b * TQn + t0 + r) * DIM + k0 + f4);
      s16x4 ha;
      #pragma unroll
      for (int j = 0; j < 4; ++j) ha[j] = f2bf(va[j]);
      *reinterpret_cast<s16x4*>(&As[r * STR + f4]) = ha;
      const int vrow = vr + i * 8;
      f32x4 vv = *reinterpret_cast<const f32x4*>(values + ((size_t)b * DIM + k0 + vrow) * DIM + v0 + vc * 4);
      const int cb = vc ^ (((vrow >> 3) & 1) << 2);
      *reinterpret_cast<f32x4*>(&Vs[vrow * VSTR + cb * 4]) = vv;
    }
    __syncthreads();
    s16x8 af[4], bfr[4];
    #pragma unroll
    for (int m = 0; m < 4; ++m)
      af[m] = *reinterpret_cast<const s16x8*>(&As[(wm + m * 16 + cl) * STR + kg * 8]);
    #pragma unroll
    for (int n = 0; n < 4; ++n){
      const int colb = wn + n * 16 + cl;
      const int cb = (colb >> 2) ^ ((kg & 1) << 2);
      #pragma unroll
      for (int j = 0; j < 8; ++j){
        const int rowv = kg * 8 + j;
        bfr[n][j] = f2bf(Vs[rowv * VSTR + cb * 4 + (colb & 3)]);
      }
    }
    #pragma unroll
    for (int m = 0; m < 4; ++m)
      #pragma unroll
      for (int n = 0; n < 4; ++n)
        acc[m][n] = __builtin_amdgcn_mfma_f32_16x16x32_bf16(af[m], bfr[n], acc[m][n], 0, 0, 0);
    __syncthreads();
  }
  #pragma unroll
  for (int m = 0; m < 4; ++m){
    const int trow = t0 + wm + m * 16 + kg * 4;
    #pragma unroll
    for (int n = 0; n < 4; ++n){
      const int vcol = v0 + wn + n * 16 + cl;
      #pragma unroll
      for (int j = 0; j < 4; ++j)
        ctx[((size_t)b * TQn + trow + j) * DIM + vcol] = acc[m][n][j];
    }
  }
}

extern "C" void kernel_launch(void* const* d_in, const int* in_sizes, int n_in,
                              void* d_out, int out_size, void* d_ws, size_t ws_size,
                              hipStream_t stream){
  (void)in_sizes; (void)n_in; (void)out_size;
  const float* query  = (const float*)d_in[0];  // [1024][16][1024] == m-major [16384][1024]
  const float* keys   = (const float*)d_in[1];  // [16][1024][1024]
  const float* values = (const float*)d_in[2];  // [16][1024][1024]
  const float* mask   = (const float*)d_in[3];  // [16][1024]
  const float* Wm     = (const float*)d_in[4];  // [1024][1024]
  float* score = (float*)d_out;                              // [16][1024][1024]
  float* ctx   = score + (size_t)NB * TQn * DIM;             // qp-plane scratch then real ctx
  dim3 blk(256, 1, 1);
  dim3 blk512(512, 1, 1);

  const size_t M16 = (size_t)16 * 1024 * 1024;   // 16M shorts
  const size_t M1  = (size_t)1024 * 1024;
  const size_t need = (5 * M16 + 2 * M1) * 2;    // 164 MB
  if (ws_size >= need){
    short* w  = (short*)d_ws;
    short* qh = w;                 // query bf16 hi
    short* ql = qh + M16;          // query bf16 lo
    short* kf = ql + M16;          // keys fp16 (single plane)
    short* wh = kf + M16;          // W bf16 hi
    short* wl = wh + M1;           // W bf16 lo
    short* vT = wl + M1;           // values^T bf16 [b][v][s]
    short* sb = vT + M16;          // score bf16
    short* qph = (short*)ctx;      // qp fp16 hi plane (m-major [16384][1024])
    short* qpl = qph + M16;        // qp fp16 lo plane

    k0_split<<<dim3(16384, 1, 1), blk, 0, stream>>>(query, qh, ql);
    k0_cvt16<<<dim3(16384, 1, 1), blk, 0, stream>>>(keys, kf);
    k0_split<<<dim3(1024, 1, 1), blk, 0, stream>>>(Wm, wh, wl);
    k0_vtrans<<<dim3(16, 16, 16), blk, 0, stream>>>(values, vT);
    // K1: qp = query . W^T (bf16 3-chain, exact) -> fp16 hi/lo planes
    gemm256<3, 2><<<dim3(4, 64, 1), blk512, 0, stream>>>(qh, ql, wh, wl,
        nullptr, qph, qpl, 1, 0, 1, 0, 0);
    // K2: logits = (qph+qpl) . kf  (fp16 2-chain)
    gemm256<2, 0><<<dim3(4, 4, 16), blk512, 0, stream>>>(qph, qpl, kf, nullptr,
        score, nullptr, nullptr, 16, 1, 1, 1024, 1024);
    k3_softmax<<<dim3(NB * TQn, 1, 1), blk, 0, stream>>>(score, mask, sb);
    // K4: ctx = score . vT (bf16 1-chain)
    gemm256<1, 0><<<dim3(4, 4, 16), blk512, 0, stream>>>(sb, nullptr, vT, nullptr,
        ctx, nullptr, nullptr, 1, 1024, 1, 1024, 1024);
  } else {
    k1_qp<<<dim3(DIM / BN, (TQn * NB) / BM, 1), blk, 0, stream>>>(query, Wm, ctx);
    k2_logits<<<dim3(DIM / BN, TQn / BM, NB), blk, 0, stream>>>(ctx, keys, score);
    k3_softmax<<<dim3(NB * TQn, 1, 1), blk, 0, stream>>>(score, mask, nullptr);
    k4_ctx<<<dim3(DIM / BN, TQn / BM, NB), blk, 0, stream>>>(score, values, ctx);
  }
}

// Round 10
// 307.671 us; speedup vs baseline: 1.3446x; 1.0819x over previous
//
#include <hip/hip_runtime.h>
#include <hip/hip_bf16.h>

#define TQn 1024
#define NB  16
#define DIM 1024
#define BM  128
#define BN  128
#define BK  32
#define STR 40
#define VSTR 132

typedef __attribute__((ext_vector_type(4))) float f32x4;
typedef __attribute__((ext_vector_type(8))) short s16x8;
typedef __attribute__((ext_vector_type(4))) short s16x4;
typedef __attribute__((ext_vector_type(8))) _Float16 h16x8;

__device__ __forceinline__ short f2bf(float f){
  union { float f; unsigned u; } v; v.f = f;
  unsigned r = v.u + 0x7fffu + ((v.u >> 16) & 1u);  // RNE
  return (short)(r >> 16);
}
__device__ __forceinline__ float bf2f(short h){
  union { unsigned u; float f; } v; v.u = ((unsigned)(unsigned short)h) << 16;
  return v.f;
}

__device__ __forceinline__ void gload16(const short* g, short* l){
#if __has_builtin(__builtin_amdgcn_global_load_lds)
  __builtin_amdgcn_global_load_lds(
      (const __attribute__((address_space(1))) unsigned int*)(const void*)g,
      (__attribute__((address_space(3))) unsigned int*)(void*)l, 16, 0, 0);
#else
  *reinterpret_cast<s16x8*>(l) = *reinterpret_cast<const s16x8*>(g);
#endif
}

// CH=2 path uses fp16 MFMA; others bf16. Same fragment geometry (8 elems, 4 VGPRs).
template<int CH>
__device__ __forceinline__ f32x4 mfma_frag(s16x8 a, s16x8 b, f32x4 c){
  if constexpr (CH == 2)
    return __builtin_amdgcn_mfma_f32_16x16x32_f16(
        __builtin_bit_cast(h16x8, a), __builtin_bit_cast(h16x8, b), c, 0, 0, 0);
  else
    return __builtin_amdgcn_mfma_f32_16x16x32_bf16(a, b, c, 0, 0, 0);
}

// ---------------- fast path ----------------

// fp32 -> fp16 hi/lo planes (residual ~2^-22 rel)
__global__ __launch_bounds__(256) void k0_split16(const float* __restrict__ in,
                                                  short* __restrict__ hi,
                                                  short* __restrict__ lo){
  const size_t i = ((size_t)blockIdx.x * 256 + threadIdx.x) * 4;
  f32x4 v = *reinterpret_cast<const f32x4*>(in + i);
  s16x4 h, l;
  #pragma unroll
  for (int j = 0; j < 4; ++j){
    _Float16 hh = (_Float16)v[j];
    h[j] = __builtin_bit_cast(short, hh);
    _Float16 ll = (_Float16)(v[j] - (float)hh);
    l[j] = __builtin_bit_cast(short, ll);
  }
  *reinterpret_cast<s16x4*>(hi + i) = h;
  *reinterpret_cast<s16x4*>(lo + i) = l;
}

// fp32 -> single fp16 plane
__global__ __launch_bounds__(256) void k0_cvt16(const float* __restrict__ in,
                                                short* __restrict__ out){
  const size_t i = ((size_t)blockIdx.x * 256 + threadIdx.x) * 4;
  f32x4 v = *reinterpret_cast<const f32x4*>(in + i);
  s16x4 o;
  #pragma unroll
  for (int j = 0; j < 4; ++j){
    _Float16 h = (_Float16)v[j];
    o[j] = __builtin_bit_cast(short, h);
  }
  *reinterpret_cast<s16x4*>(out + i) = o;
}

// values [b][s][v] fp32 -> vT [b][v][s] bf16
__global__ __launch_bounds__(256) void k0_vtrans(const float* __restrict__ vals,
                                                 short* __restrict__ vT){
  __shared__ short T[64 * 72];
  const int t = threadIdx.x;
  const int v0 = blockIdx.x * 64, s0 = blockIdx.y * 64, b = blockIdx.z;
  const int r16 = t >> 4, c4 = (t & 15) * 4;
  #pragma unroll
  for (int i = 0; i < 4; ++i){
    const int sl = i * 16 + r16;
    f32x4 v = *reinterpret_cast<const f32x4*>(vals + ((size_t)b * TQn + s0 + sl) * DIM + v0 + c4);
    #pragma unroll
    for (int j = 0; j < 4; ++j) T[(c4 + j) * 72 + sl] = f2bf(v[j]);
  }
  __syncthreads();
  #pragma unroll
  for (int i = 0; i < 4; ++i){
    const int vl = i * 16 + r16;
    s16x4 o = *reinterpret_cast<const s16x4*>(&T[vl * 72 + c4]);
    *reinterpret_cast<s16x4*>(vT + ((size_t)b * DIM + v0 + vl) * TQn + s0 + c4) = o;
  }
}

// 256x256 A*B^T GEMM, 8 waves (2Mx4N), BK=64, dbuf 128KB, fragment-major
// (conflict-free b128), counted-vmcnt pipeline (round-8 proven structure).
// CH=3: bf16 virtual-K 3x1024 (Ah*Bh + Al*Bh + Ah*Bl)
// CH=2: fp16 virtual-K 2x1024 (Ah*B + Al*B), B single plane
// CH=1: bf16 plain 1024
// EPI: 0 = fp32 C; 1 = bf16 hi/lo planes; 2 = fp16 hi/lo planes
template<int CH, int EPI>
__global__ __launch_bounds__(512, 2) void gemm256(
    const short* __restrict__ Ah, const short* __restrict__ Al,
    const short* __restrict__ Bh, const short* __restrict__ Bl,
    float* __restrict__ C, short* __restrict__ Ch, short* __restrict__ Cl,
    int ARS, int ABO, int BRS, int BBO, int CBO)
{
  constexpr int NSTEP = (CH == 3) ? 48 : (CH == 2) ? 32 : 16;
  __shared__ __align__(16) short lds[2 * 32768];   // 128 KB
  const int tid = threadIdx.x;
  const int lane = tid & 63, w = tid >> 6;
  const int cl = lane & 15, kg = lane >> 4;
  const int lane8 = lane * 8;
  const int bx = blockIdx.x, by = blockIdx.y, bz = blockIdx.z;
  const int wr = w >> 2, wc = w & 3;

  int aoffE[2], boffE[2], aldsE[2], bldsE[2];
  #pragma unroll
  for (int l = 0; l < 2; ++l){
    const int rg = 2 * w + l;
    const int arow = by * 256 + rg * 16 + cl;
    const int brow = bx * 256 + rg * 16 + cl;
    aoffE[l] = (arow * ARS + bz * ABO) * 1024 + kg * 8;
    boffE[l] = (brow * BRS + bz * BBO) * 1024 + kg * 8;
    aldsE[l] = (4 * w + 2 * l) * 512 + lane8;
    bldsE[l] = 16384 + (4 * w + 2 * l) * 512 + lane8;
  }

  f32x4 acc[8][4] = {};

  // prologue: stage tile 0 (chain 0 -> Ah,Bh) in deadline order; kk1 stays in flight.
  #pragma unroll
  for (int l = 0; l < 2; ++l) gload16(Bh + (size_t)boffE[l], &lds[bldsE[l]]);
  #pragma unroll
  for (int l = 0; l < 2; ++l) gload16(Ah + (size_t)aoffE[l], &lds[aldsE[l]]);
  #pragma unroll
  for (int l = 0; l < 2; ++l) gload16(Bh + (size_t)(boffE[l] + 32), &lds[bldsE[l] + 512]);
  #pragma unroll
  for (int l = 0; l < 2; ++l) gload16(Ah + (size_t)(aoffE[l] + 32), &lds[aldsE[l] + 512]);
  asm volatile("s_waitcnt vmcnt(4)" ::: "memory");
  __builtin_amdgcn_s_barrier();
  __builtin_amdgcn_sched_barrier(0);

  for (int t = 0; t < NSTEP; ++t){
    const int buf = (t & 1) * 32768;
    const int nbuf = buf ^ 32768;
    const bool pf = (t + 1 < NSTEP);
    int k1 = 0; const short *PA = Ah, *PB = Bh;
    if (pf){
      if (CH == 3){
        const int cc = (t + 1) % 3;
        k1 = ((t + 1) / 3) * 64;
        PA = (cc == 1) ? Al : Ah;
        PB = (cc == 2) ? Bl : Bh;
      } else if (CH == 2){
        k1 = ((t + 1) >> 1) * 64;
        PA = ((t + 1) & 1) ? Al : Ah;
        PB = Bh;
      } else k1 = (t + 1) * 64;
    }

    s16x8 av[4], bv[4];
    // ---- ph0: quad (m0-3, kk0) ----
    #pragma unroll
    for (int m = 0; m < 4; ++m)
      av[m] = *reinterpret_cast<const s16x8*>(&lds[buf + ((wr * 8 + m) * 2 + 0) * 512 + lane8]);
    #pragma unroll
    for (int n = 0; n < 4; ++n)
      bv[n] = *reinterpret_cast<const s16x8*>(&lds[buf + 16384 + ((wc * 4 + n) * 2 + 0) * 512 + lane8]);
    if (pf){
      #pragma unroll
      for (int l = 0; l < 2; ++l) gload16(PB + (size_t)(boffE[l] + k1), &lds[nbuf + bldsE[l]]);
    }
    __builtin_amdgcn_s_barrier();
    __builtin_amdgcn_s_setprio(1);
    #pragma unroll
    for (int m = 0; m < 4; ++m)
      #pragma unroll
      for (int n = 0; n < 4; ++n)
        acc[m][n] = mfma_frag<CH>(av[m], bv[n], acc[m][n]);
    __builtin_amdgcn_s_setprio(0);
    __builtin_amdgcn_s_barrier();
    // ---- ph1: quad (m4-7, kk0), bv reused ----
    #pragma unroll
    for (int m = 0; m < 4; ++m)
      av[m] = *reinterpret_cast<const s16x8*>(&lds[buf + ((wr * 8 + 4 + m) * 2 + 0) * 512 + lane8]);
    if (pf){
      #pragma unroll
      for (int l = 0; l < 2; ++l) gload16(PA + (size_t)(aoffE[l] + k1), &lds[nbuf + aldsE[l]]);
    }
    __builtin_amdgcn_s_barrier();
    __builtin_amdgcn_s_setprio(1);
    #pragma unroll
    for (int m = 0; m < 4; ++m)
      #pragma unroll
      for (int n = 0; n < 4; ++n)
        acc[4 + m][n] = mfma_frag<CH>(av[m], bv[n], acc[4 + m][n]);
    __builtin_amdgcn_s_setprio(0);
    if (pf) asm volatile("s_waitcnt vmcnt(4)" ::: "memory");
    else    asm volatile("s_waitcnt vmcnt(0)" ::: "memory");
    __builtin_amdgcn_s_barrier();
    __builtin_amdgcn_sched_barrier(0);
    // ---- ph2: quad (m0-3, kk1) ----
    #pragma unroll
    for (int m = 0; m < 4; ++m)
      av[m] = *reinterpret_cast<const s16x8*>(&lds[buf + ((wr * 8 + m) * 2 + 1) * 512 + lane8]);
    #pragma unroll
    for (int n = 0; n < 4; ++n)
      bv[n] = *reinterpret_cast<const s16x8*>(&lds[buf + 16384 + ((wc * 4 + n) * 2 + 1) * 512 + lane8]);
    if (pf){
      #pragma unroll
      for (int l = 0; l < 2; ++l) gload16(PB + (size_t)(boffE[l] + k1 + 32), &lds[nbuf + bldsE[l] + 512]);
    }
    __builtin_amdgcn_s_barrier();
    __builtin_amdgcn_s_setprio(1);
    #pragma unroll
    for (int m = 0; m < 4; ++m)
      #pragma unroll
      for (int n = 0; n < 4; ++n)
        acc[m][n] = mfma_frag<CH>(av[m], bv[n], acc[m][n]);
    __builtin_amdgcn_s_setprio(0);
    __builtin_amdgcn_s_barrier();
    // ---- ph3: quad (m4-7, kk1), bv reused ----
    #pragma unroll
    for (int m = 0; m < 4; ++m)
      av[m] = *reinterpret_cast<const s16x8*>(&lds[buf + ((wr * 8 + 4 + m) * 2 + 1) * 512 + lane8]);
    if (pf){
      #pragma unroll
      for (int l = 0; l < 2; ++l) gload16(PA + (size_t)(aoffE[l] + k1 + 32), &lds[nbuf + aldsE[l] + 512]);
    }
    __builtin_amdgcn_s_barrier();
    __builtin_amdgcn_s_setprio(1);
    #pragma unroll
    for (int m = 0; m < 4; ++m)
      #pragma unroll
      for (int n = 0; n < 4; ++n)
        acc[4 + m][n] = mfma_frag<CH>(av[m], bv[n], acc[4 + m][n]);
    __builtin_amdgcn_s_setprio(0);
    if (pf){
      asm volatile("s_waitcnt vmcnt(4)" ::: "memory");
      __builtin_amdgcn_s_barrier();
      __builtin_amdgcn_sched_barrier(0);
    }
  }

  #pragma unroll
  for (int m = 0; m < 8; ++m){
    const int row0 = by * 256 + wr * 128 + m * 16 + kg * 4;
    #pragma unroll
    for (int n = 0; n < 4; ++n){
      const int col = bx * 256 + wc * 64 + n * 16 + cl;
      #pragma unroll
      for (int j = 0; j < 4; ++j){
        const size_t off = ((size_t)(row0 + j) + (size_t)bz * CBO) * 1024 + col;
        if (EPI == 0) C[off] = acc[m][n][j];
        else if (EPI == 1){
          const float v = acc[m][n][j];
          const short hh = f2bf(v);
          Ch[off] = hh; Cl[off] = f2bf(v - bf2f(hh));
        } else {
          const float v = acc[m][n][j];
          const _Float16 hh = (_Float16)v;
          Ch[off] = __builtin_bit_cast(short, hh);
          const _Float16 ll = (_Float16)(v - (float)hh);
          Cl[off] = __builtin_bit_cast(short, ll);
        }
      }
    }
  }
}

// K3: in-place row softmax of (logits + mask[b][s]); optional bf16 copy for K4
__global__ __launch_bounds__(256) void k3_softmax(float* __restrict__ logits,
                                                  const float* __restrict__ mask,
                                                  short* __restrict__ sbf){
  const int row = blockIdx.x;       // b*TQ + t
  const int b = row >> 10;
  const int tid = threadIdx.x;
  float* p = logits + (size_t)row * DIM;
  f32x4 v  = *reinterpret_cast<const f32x4*>(p + tid * 4);
  f32x4 mk = *reinterpret_cast<const f32x4*>(mask + (size_t)b * DIM + tid * 4);
  v = v + mk;
  float mx = fmaxf(fmaxf(v[0], v[1]), fmaxf(v[2], v[3]));
  #pragma unroll
  for (int off = 32; off; off >>= 1) mx = fmaxf(mx, __shfl_xor(mx, off));
  __shared__ float red[8];
  const int lane = tid & 63, wid = tid >> 6;
  if (lane == 0) red[wid] = mx;
  __syncthreads();
  mx = fmaxf(fmaxf(red[0], red[1]), fmaxf(red[2], red[3]));
  f32x4 e;
  #pragma unroll
  for (int j = 0; j < 4; ++j) e[j] = __expf(v[j] - mx);
  float s = e[0] + e[1] + e[2] + e[3];
  #pragma unroll
  for (int off = 32; off; off >>= 1) s += __shfl_xor(s, off);
  if (lane == 0) red[4 + wid] = s;
  __syncthreads();
  s = red[4] + red[5] + red[6] + red[7];
  const float inv = 1.0f / s;
  f32x4 o;
  s16x4 ob;
  #pragma unroll
  for (int j = 0; j < 4; ++j){ o[j] = e[j] * inv; ob[j] = f2bf(o[j]); }
  *reinterpret_cast<f32x4*>(p + tid * 4) = o;
  if (sbf) *reinterpret_cast<s16x4*>(sbf + (size_t)row * DIM + tid * 4) = ob;
}

// ---------------- fallback (round-3 passing) kernels ----------------

__global__ __launch_bounds__(256) void k1_qp(const float* __restrict__ A,
                                             const float* __restrict__ Wm,
                                             float* __restrict__ C){
  __shared__ __align__(16) short Ah[BM * STR];
  __shared__ __align__(16) short Al[BM * STR];
  __shared__ __align__(16) short Bh[BN * STR];
  __shared__ __align__(16) short Bl[BN * STR];
  const int tid = threadIdx.x;
  const int m0 = blockIdx.y * BM, n0 = blockIdx.x * BN;
  const int lane = tid & 63, wid = tid >> 6;
  const int wm = (wid >> 1) * 64, wn = (wid & 1) * 64;
  const int cl = lane & 15, kg = lane >> 4;
  const int rr = tid >> 3, f4 = (tid & 7) * 4;
  f32x4 acc[4][4] = {};
  for (int k0 = 0; k0 < DIM; k0 += BK){
    #pragma unroll
    for (int i = 0; i < 4; ++i){
      const int r = rr + i * 32;
      f32x4 va = *reinterpret_cast<const f32x4*>(A  + (size_t)(m0 + r) * DIM + k0 + f4);
      f32x4 vb = *reinterpret_cast<const f32x4*>(Wm + (size_t)(n0 + r) * DIM + k0 + f4);
      s16x4 ha, la, hb, lb;
      #pragma unroll
      for (int j = 0; j < 4; ++j){
        ha[j] = f2bf(va[j]); la[j] = f2bf(va[j] - bf2f(ha[j]));
        hb[j] = f2bf(vb[j]); lb[j] = f2bf(vb[j] - bf2f(hb[j]));
      }
      *reinterpret_cast<s16x4*>(&Ah[r * STR + f4]) = ha;
      *reinterpret_cast<s16x4*>(&Al[r * STR + f4]) = la;
      *reinterpret_cast<s16x4*>(&Bh[r * STR + f4]) = hb;
      *reinterpret_cast<s16x4*>(&Bl[r * STR + f4]) = lb;
    }
    __syncthreads();
    s16x8 ah[4], al8[4], bh8[4], bl8[4];
    #pragma unroll
    for (int m = 0; m < 4; ++m){
      ah[m]  = *reinterpret_cast<const s16x8*>(&Ah[(wm + m * 16 + cl) * STR + kg * 8]);
      al8[m] = *reinterpret_cast<const s16x8*>(&Al[(wm + m * 16 + cl) * STR + kg * 8]);
    }
    #pragma unroll
    for (int n = 0; n < 4; ++n){
      bh8[n] = *reinterpret_cast<const s16x8*>(&Bh[(wn + n * 16 + cl) * STR + kg * 8]);
      bl8[n] = *reinterpret_cast<const s16x8*>(&Bl[(wn + n * 16 + cl) * STR + kg * 8]);
    }
    #pragma unroll
    for (int m = 0; m < 4; ++m)
      #pragma unroll
      for (int n = 0; n < 4; ++n){
        acc[m][n] = __builtin_amdgcn_mfma_f32_16x16x32_bf16(ah[m],  bh8[n], acc[m][n], 0, 0, 0);
        acc[m][n] = __builtin_amdgcn_mfma_f32_16x16x32_bf16(al8[m], bh8[n], acc[m][n], 0, 0, 0);
        acc[m][n] = __builtin_amdgcn_mfma_f32_16x16x32_bf16(ah[m],  bl8[n], acc[m][n], 0, 0, 0);
      }
    __syncthreads();
  }
  #pragma unroll
  for (int m = 0; m < 4; ++m){
    const int row = m0 + wm + m * 16 + kg * 4;
    #pragma unroll
    for (int n = 0; n < 4; ++n){
      const int col = n0 + wn + n * 16 + cl;
      #pragma unroll
      for (int j = 0; j < 4; ++j)
        C[(size_t)(row + j) * DIM + col] = acc[m][n][j];
    }
  }
}

__global__ __launch_bounds__(256) void k2_logits(const float* __restrict__ qp,
                                                 const float* __restrict__ keys,
                                                 float* __restrict__ out){
  __shared__ __align__(16) short Ah[BM * STR];
  __shared__ __align__(16) short Al[BM * STR];
  __shared__ __align__(16) short Bh[BN * STR];
  __shared__ __align__(16) short Bl[BN * STR];
  const int tid = threadIdx.x;
  const int b = blockIdx.z;
  const int t0 = blockIdx.y * BM, s0 = blockIdx.x * BN;
  const int lane = tid & 63, wid = tid >> 6;
  const int wm = (wid >> 1) * 64, wn = (wid & 1) * 64;
  const int cl = lane & 15, kg = lane >> 4;
  const int rr = tid >> 3, f4 = (tid & 7) * 4;
  f32x4 acc[4][4] = {};
  for (int k0 = 0; k0 < DIM; k0 += BK){
    #pragma unroll
    for (int i = 0; i < 4; ++i){
      const int r = rr + i * 32;
      f32x4 va = *reinterpret_cast<const f32x4*>(qp   + (size_t)((t0 + r) * NB + b) * DIM + k0 + f4);
      f32x4 vb = *reinterpret_cast<const f32x4*>(keys + ((size_t)b * DIM + s0 + r) * DIM + k0 + f4);
      s16x4 ha, la, hb, lb;
      #pragma unroll
      for (int j = 0; j < 4; ++j){
        ha[j] = f2bf(va[j]); la[j] = f2bf(va[j] - bf2f(ha[j]));
        hb[j] = f2bf(vb[j]); lb[j] = f2bf(vb[j] - bf2f(hb[j]));
      }
      *reinterpret_cast<s16x4*>(&Ah[r * STR + f4]) = ha;
      *reinterpret_cast<s16x4*>(&Al[r * STR + f4]) = la;
      *reinterpret_cast<s16x4*>(&Bh[r * STR + f4]) = hb;
      *reinterpret_cast<s16x4*>(&Bl[r * STR + f4]) = lb;
    }
    __syncthreads();
    s16x8 ah[4], al8[4], bh8[4], bl8[4];
    #pragma unroll
    for (int m = 0; m < 4; ++m){
      ah[m]  = *reinterpret_cast<const s16x8*>(&Ah[(wm + m * 16 + cl) * STR + kg * 8]);
      al8[m] = *reinterpret_cast<const s16x8*>(&Al[(wm + m * 16 + cl) * STR + kg * 8]);
    }
    #pragma unroll
    for (int n = 0; n < 4; ++n){
      bh8[n] = *reinterpret_cast<const s16x8*>(&Bh[(wn + n * 16 + cl) * STR + kg * 8]);
      bl8[n] = *reinterpret_cast<const s16x8*>(&Bl[(wn + n * 16 + cl) * STR + kg * 8]);
    }
    #pragma unroll
    for (int m = 0; m < 4; ++m)
      #pragma unroll
      for (int n = 0; n < 4; ++n){
        acc[m][n] = __builtin_amdgcn_mfma_f32_16x16x32_bf16(ah[m],  bh8[n], acc[m][n], 0, 0, 0);
        acc[m][n] = __builtin_amdgcn_mfma_f32_16x16x32_bf16(al8[m], bh8[n], acc[m][n], 0, 0, 0);
        acc[m][n] = __builtin_amdgcn_mfma_f32_16x16x32_bf16(ah[m],  bl8[n], acc[m][n], 0, 0, 0);
      }
    __syncthreads();
  }
  #pragma unroll
  for (int m = 0; m < 4; ++m){
    const int trow = t0 + wm + m * 16 + kg * 4;
    #pragma unroll
    for (int n = 0; n < 4; ++n){
      const int scol = s0 + wn + n * 16 + cl;
      #pragma unroll
      for (int j = 0; j < 4; ++j)
        out[((size_t)b * TQn + trow + j) * DIM + scol] = acc[m][n][j];
    }
  }
}

__global__ __launch_bounds__(256) void k4_ctx(const float* __restrict__ score,
                                              const float* __restrict__ values,
                                              float* __restrict__ ctx){
  __shared__ __align__(16) short As[BM * STR];
  __shared__ __align__(16) float Vs[BK * VSTR];
  const int tid = threadIdx.x;
  const int b = blockIdx.z;
  const int t0 = blockIdx.y * BM, v0 = blockIdx.x * BN;
  const int lane = tid & 63, wid = tid >> 6;
  const int wm = (wid >> 1) * 64, wn = (wid & 1) * 64;
  const int cl = lane & 15, kg = lane >> 4;
  const int rr = tid >> 3, f4 = (tid & 7) * 4;
  const int vr = tid >> 5, vc = tid & 31;
  f32x4 acc[4][4] = {};
  for (int k0 = 0; k0 < DIM; k0 += BK){
    #pragma unroll
    for (int i = 0; i < 4; ++i){
      const int r = rr + i * 32;
      f32x4 va = *reinterpret_cast<const f32x4*>(score + ((size_t)b * TQn + t0 + r) * DIM + k0 + f4);
      s16x4 ha;
      #pragma unroll
      for (int j = 0; j < 4; ++j) ha[j] = f2bf(va[j]);
      *reinterpret_cast<s16x4*>(&As[r * STR + f4]) = ha;
      const int vrow = vr + i * 8;
      f32x4 vv = *reinterpret_cast<const f32x4*>(values + ((size_t)b * DIM + k0 + vrow) * DIM + v0 + vc * 4);
      const int cb = vc ^ (((vrow >> 3) & 1) << 2);
      *reinterpret_cast<f32x4*>(&Vs[vrow * VSTR + cb * 4]) = vv;
    }
    __syncthreads();
    s16x8 af[4], bfr[4];
    #pragma unroll
    for (int m = 0; m < 4; ++m)
      af[m] = *reinterpret_cast<const s16x8*>(&As[(wm + m * 16 + cl) * STR + kg * 8]);
    #pragma unroll
    for (int n = 0; n < 4; ++n){
      const int colb = wn + n * 16 + cl;
      const int cb = (colb >> 2) ^ ((kg & 1) << 2);
      #pragma unroll
      for (int j = 0; j < 8; ++j){
        const int rowv = kg * 8 + j;
        bfr[n][j] = f2bf(Vs[rowv * VSTR + cb * 4 + (colb & 3)]);
      }
    }
    #pragma unroll
    for (int m = 0; m < 4; ++m)
      #pragma unroll
      for (int n = 0; n < 4; ++n)
        acc[m][n] = __builtin_amdgcn_mfma_f32_16x16x32_bf16(af[m], bfr[n], acc[m][n], 0, 0, 0);
    __syncthreads();
  }
  #pragma unroll
  for (int m = 0; m < 4; ++m){
    const int trow = t0 + wm + m * 16 + kg * 4;
    #pragma unroll
    for (int n = 0; n < 4; ++n){
      const int vcol = v0 + wn + n * 16 + cl;
      #pragma unroll
      for (int j = 0; j < 4; ++j)
        ctx[((size_t)b * TQn + trow + j) * DIM + vcol] = acc[m][n][j];
    }
  }
}

extern "C" void kernel_launch(void* const* d_in, const int* in_sizes, int n_in,
                              void* d_out, int out_size, void* d_ws, size_t ws_size,
                              hipStream_t stream){
  (void)in_sizes; (void)n_in; (void)out_size;
  const float* query  = (const float*)d_in[0];  // [1024][16][1024] == m-major [16384][1024]
  const float* keys   = (const float*)d_in[1];  // [16][1024][1024]
  const float* values = (const float*)d_in[2];  // [16][1024][1024]
  const float* mask   = (const float*)d_in[3];  // [16][1024]
  const float* Wm     = (const float*)d_in[4];  // [1024][1024]
  float* score = (float*)d_out;                              // [16][1024][1024]
  float* ctx   = score + (size_t)NB * TQn * DIM;             // qp-plane scratch then real ctx
  dim3 blk(256, 1, 1);
  dim3 blk512(512, 1, 1);

  const size_t M16 = (size_t)16 * 1024 * 1024;   // 16M shorts
  const size_t M1  = (size_t)1024 * 1024;
  const size_t need = (5 * M16 + M1) * 2;        // 162 MB
  if (ws_size >= need){
    short* w  = (short*)d_ws;
    short* qh = w;                 // query fp16 hi
    short* ql = qh + M16;          // query fp16 lo
    short* kf = ql + M16;          // keys fp16 (single plane)
    short* wf = kf + M16;          // W fp16 (single plane)
    short* vT = wf + M1;           // values^T bf16 [b][v][s]
    short* sb = vT + M16;          // score bf16
    short* qph = (short*)ctx;      // qp fp16 hi plane (m-major [16384][1024])
    short* qpl = qph + M16;        // qp fp16 lo plane

    k0_split16<<<dim3(16384, 1, 1), blk, 0, stream>>>(query, qh, ql);
    k0_cvt16<<<dim3(16384, 1, 1), blk, 0, stream>>>(keys, kf);
    k0_cvt16<<<dim3(1024, 1, 1), blk, 0, stream>>>(Wm, wf);
    k0_vtrans<<<dim3(16, 16, 16), blk, 0, stream>>>(values, vT);
    // K1: qp = (qh+ql) . wf^T  (fp16 2-chain) -> fp16 hi/lo planes
    gemm256<2, 2><<<dim3(4, 64, 1), blk512, 0, stream>>>(qh, ql, wf, nullptr,
        nullptr, qph, qpl, 1, 0, 1, 0, 0);
    // K2: logits = (qph+qpl) . kf  (fp16 2-chain)
    gemm256<2, 0><<<dim3(4, 4, 16), blk512, 0, stream>>>(qph, qpl, kf, nullptr,
        score, nullptr, nullptr, 16, 1, 1, 1024, 1024);
    k3_softmax<<<dim3(NB * TQn, 1, 1), blk, 0, stream>>>(score, mask, sb);
    // K4: ctx = score . vT (bf16 1-chain)
    gemm256<1, 0><<<dim3(4, 4, 16), blk512, 0, stream>>>(sb, nullptr, vT, nullptr,
        ctx, nullptr, nullptr, 1, 1024, 1, 1024, 1024);
  } else {
    k1_qp<<<dim3(DIM / BN, (TQn * NB) / BM, 1), blk, 0, stream>>>(query, Wm, ctx);
    k2_logits<<<dim3(DIM / BN, TQn / BM, NB), blk, 0, stream>>>(ctx, keys, score);
    k3_softmax<<<dim3(NB * TQn, 1, 1), blk, 0, stream>>>(score, mask, nullptr);
    k4_ctx<<<dim3(DIM / BN, TQn / BM, NB), blk, 0, stream>>>(score, values, ctx);
  }
}

// Round 11
// 268.560 us; speedup vs baseline: 1.5404x; 1.1456x over previous
//
#include <hip/hip_runtime.h>
#include <hip/hip_bf16.h>

#define TQn 1024
#define NB  16
#define DIM 1024
#define BM  128
#define BN  128
#define BK  32
#define STR 40
#define VSTR 132

typedef __attribute__((ext_vector_type(4))) float f32x4;
typedef __attribute__((ext_vector_type(8))) short s16x8;
typedef __attribute__((ext_vector_type(4))) short s16x4;
typedef __attribute__((ext_vector_type(8))) _Float16 h16x8;

__device__ __forceinline__ short f2bf(float f){
  union { float f; unsigned u; } v; v.f = f;
  unsigned r = v.u + 0x7fffu + ((v.u >> 16) & 1u);  // RNE
  return (short)(r >> 16);
}
__device__ __forceinline__ float bf2f(short h){
  union { unsigned u; float f; } v; v.u = ((unsigned)(unsigned short)h) << 16;
  return v.f;
}
__device__ __forceinline__ short f2h(float f){
  _Float16 h = (_Float16)f;
  return __builtin_bit_cast(short, h);
}

__device__ __forceinline__ void gload16(const short* g, short* l){
#if __has_builtin(__builtin_amdgcn_global_load_lds)
  __builtin_amdgcn_global_load_lds(
      (const __attribute__((address_space(1))) unsigned int*)(const void*)g,
      (__attribute__((address_space(3))) unsigned int*)(void*)l, 16, 0, 0);
#else
  *reinterpret_cast<s16x8*>(l) = *reinterpret_cast<const s16x8*>(g);
#endif
}

// CH=2 (fp16 2-chain) and CH=4 (fp16 1-chain) use fp16 MFMA; CH=1/3 bf16.
template<int CH>
__device__ __forceinline__ f32x4 mfma_frag(s16x8 a, s16x8 b, f32x4 c){
  if constexpr (CH == 2 || CH == 4)
    return __builtin_amdgcn_mfma_f32_16x16x32_f16(
        __builtin_bit_cast(h16x8, a), __builtin_bit_cast(h16x8, b), c, 0, 0, 0);
  else
    return __builtin_amdgcn_mfma_f32_16x16x32_bf16(a, b, c, 0, 0, 0);
}

// ---------------- fast path ----------------

// fp32 -> single fp16 plane
__global__ __launch_bounds__(256) void k0_cvt16(const float* __restrict__ in,
                                                short* __restrict__ out){
  const size_t i = ((size_t)blockIdx.x * 256 + threadIdx.x) * 4;
  f32x4 v = *reinterpret_cast<const f32x4*>(in + i);
  s16x4 o;
  #pragma unroll
  for (int j = 0; j < 4; ++j) o[j] = f2h(v[j]);
  *reinterpret_cast<s16x4*>(out + i) = o;
}

// values [b][s][v] fp32 -> vT [b][v][s] fp16
__global__ __launch_bounds__(256) void k0_vtrans(const float* __restrict__ vals,
                                                 short* __restrict__ vT){
  __shared__ short T[64 * 72];
  const int t = threadIdx.x;
  const int v0 = blockIdx.x * 64, s0 = blockIdx.y * 64, b = blockIdx.z;
  const int r16 = t >> 4, c4 = (t & 15) * 4;
  #pragma unroll
  for (int i = 0; i < 4; ++i){
    const int sl = i * 16 + r16;
    f32x4 v = *reinterpret_cast<const f32x4*>(vals + ((size_t)b * TQn + s0 + sl) * DIM + v0 + c4);
    #pragma unroll
    for (int j = 0; j < 4; ++j) T[(c4 + j) * 72 + sl] = f2h(v[j]);
  }
  __syncthreads();
  #pragma unroll
  for (int i = 0; i < 4; ++i){
    const int vl = i * 16 + r16;
    s16x4 o = *reinterpret_cast<const s16x4*>(&T[vl * 72 + c4]);
    *reinterpret_cast<s16x4*>(vT + ((size_t)b * DIM + v0 + vl) * TQn + s0 + c4) = o;
  }
}

// 256x256 A*B^T GEMM, 8 waves (2Mx4N), BK=64, dbuf 128KB, fragment-major
// (conflict-free b128), counted-vmcnt pipeline (round-8 proven structure).
// CH=3: bf16 virtual-K 3x1024 (Ah*Bh + Al*Bh + Ah*Bl)
// CH=2: fp16 virtual-K 2x1024 (Ah*B + Al*B), B single plane
// CH=1: bf16 plain 1024 ; CH=4: fp16 plain 1024
// EPI: 0 = fp32 C; 1 = bf16 hi/lo planes; 2 = fp16 hi/lo planes
template<int CH, int EPI>
__global__ __launch_bounds__(512, 2) void gemm256(
    const short* __restrict__ Ah, const short* __restrict__ Al,
    const short* __restrict__ Bh, const short* __restrict__ Bl,
    float* __restrict__ C, short* __restrict__ Ch, short* __restrict__ Cl,
    int ARS, int ABO, int BRS, int BBO, int CBO)
{
  constexpr int NSTEP = (CH == 3) ? 48 : (CH == 2) ? 32 : 16;
  __shared__ __align__(16) short lds[2 * 32768];   // 128 KB
  const int tid = threadIdx.x;
  const int lane = tid & 63, w = tid >> 6;
  const int cl = lane & 15, kg = lane >> 4;
  const int lane8 = lane * 8;
  const int bx = blockIdx.x, by = blockIdx.y, bz = blockIdx.z;
  const int wr = w >> 2, wc = w & 3;

  int aoffE[2], boffE[2], aldsE[2], bldsE[2];
  #pragma unroll
  for (int l = 0; l < 2; ++l){
    const int rg = 2 * w + l;
    const int arow = by * 256 + rg * 16 + cl;
    const int brow = bx * 256 + rg * 16 + cl;
    aoffE[l] = (arow * ARS + bz * ABO) * 1024 + kg * 8;
    boffE[l] = (brow * BRS + bz * BBO) * 1024 + kg * 8;
    aldsE[l] = (4 * w + 2 * l) * 512 + lane8;
    bldsE[l] = 16384 + (4 * w + 2 * l) * 512 + lane8;
  }

  f32x4 acc[8][4] = {};

  // prologue: stage tile 0 (chain 0 -> Ah,Bh) in deadline order; kk1 stays in flight.
  #pragma unroll
  for (int l = 0; l < 2; ++l) gload16(Bh + (size_t)boffE[l], &lds[bldsE[l]]);
  #pragma unroll
  for (int l = 0; l < 2; ++l) gload16(Ah + (size_t)aoffE[l], &lds[aldsE[l]]);
  #pragma unroll
  for (int l = 0; l < 2; ++l) gload16(Bh + (size_t)(boffE[l] + 32), &lds[bldsE[l] + 512]);
  #pragma unroll
  for (int l = 0; l < 2; ++l) gload16(Ah + (size_t)(aoffE[l] + 32), &lds[aldsE[l] + 512]);
  asm volatile("s_waitcnt vmcnt(4)" ::: "memory");
  __builtin_amdgcn_s_barrier();
  __builtin_amdgcn_sched_barrier(0);

  for (int t = 0; t < NSTEP; ++t){
    const int buf = (t & 1) * 32768;
    const int nbuf = buf ^ 32768;
    const bool pf = (t + 1 < NSTEP);
    int k1 = 0; const short *PA = Ah, *PB = Bh;
    if (pf){
      if (CH == 3){
        const int cc = (t + 1) % 3;
        k1 = ((t + 1) / 3) * 64;
        PA = (cc == 1) ? Al : Ah;
        PB = (cc == 2) ? Bl : Bh;
      } else if (CH == 2){
        k1 = ((t + 1) >> 1) * 64;
        PA = ((t + 1) & 1) ? Al : Ah;
        PB = Bh;
      } else k1 = (t + 1) * 64;
    }

    s16x8 av[4], bv[4];
    // ---- ph0: quad (m0-3, kk0) ----
    #pragma unroll
    for (int m = 0; m < 4; ++m)
      av[m] = *reinterpret_cast<const s16x8*>(&lds[buf + ((wr * 8 + m) * 2 + 0) * 512 + lane8]);
    #pragma unroll
    for (int n = 0; n < 4; ++n)
      bv[n] = *reinterpret_cast<const s16x8*>(&lds[buf + 16384 + ((wc * 4 + n) * 2 + 0) * 512 + lane8]);
    if (pf){
      #pragma unroll
      for (int l = 0; l < 2; ++l) gload16(PB + (size_t)(boffE[l] + k1), &lds[nbuf + bldsE[l]]);
    }
    __builtin_amdgcn_s_barrier();
    __builtin_amdgcn_s_setprio(1);
    #pragma unroll
    for (int m = 0; m < 4; ++m)
      #pragma unroll
      for (int n = 0; n < 4; ++n)
        acc[m][n] = mfma_frag<CH>(av[m], bv[n], acc[m][n]);
    __builtin_amdgcn_s_setprio(0);
    __builtin_amdgcn_s_barrier();
    // ---- ph1: quad (m4-7, kk0), bv reused ----
    #pragma unroll
    for (int m = 0; m < 4; ++m)
      av[m] = *reinterpret_cast<const s16x8*>(&lds[buf + ((wr * 8 + 4 + m) * 2 + 0) * 512 + lane8]);
    if (pf){
      #pragma unroll
      for (int l = 0; l < 2; ++l) gload16(PA + (size_t)(aoffE[l] + k1), &lds[nbuf + aldsE[l]]);
    }
    __builtin_amdgcn_s_barrier();
    __builtin_amdgcn_s_setprio(1);
    #pragma unroll
    for (int m = 0; m < 4; ++m)
      #pragma unroll
      for (int n = 0; n < 4; ++n)
        acc[4 + m][n] = mfma_frag<CH>(av[m], bv[n], acc[4 + m][n]);
    __builtin_amdgcn_s_setprio(0);
    if (pf) asm volatile("s_waitcnt vmcnt(4)" ::: "memory");
    else    asm volatile("s_waitcnt vmcnt(0)" ::: "memory");
    __builtin_amdgcn_s_barrier();
    __builtin_amdgcn_sched_barrier(0);
    // ---- ph2: quad (m0-3, kk1) ----
    #pragma unroll
    for (int m = 0; m < 4; ++m)
      av[m] = *reinterpret_cast<const s16x8*>(&lds[buf + ((wr * 8 + m) * 2 + 1) * 512 + lane8]);
    #pragma unroll
    for (int n = 0; n < 4; ++n)
      bv[n] = *reinterpret_cast<const s16x8*>(&lds[buf + 16384 + ((wc * 4 + n) * 2 + 1) * 512 + lane8]);
    if (pf){
      #pragma unroll
      for (int l = 0; l < 2; ++l) gload16(PB + (size_t)(boffE[l] + k1 + 32), &lds[nbuf + bldsE[l] + 512]);
    }
    __builtin_amdgcn_s_barrier();
    __builtin_amdgcn_s_setprio(1);
    #pragma unroll
    for (int m = 0; m < 4; ++m)
      #pragma unroll
      for (int n = 0; n < 4; ++n)
        acc[m][n] = mfma_frag<CH>(av[m], bv[n], acc[m][n]);
    __builtin_amdgcn_s_setprio(0);
    __builtin_amdgcn_s_barrier();
    // ---- ph3: quad (m4-7, kk1), bv reused ----
    #pragma unroll
    for (int m = 0; m < 4; ++m)
      av[m] = *reinterpret_cast<const s16x8*>(&lds[buf + ((wr * 8 + 4 + m) * 2 + 1) * 512 + lane8]);
    if (pf){
      #pragma unroll
      for (int l = 0; l < 2; ++l) gload16(PA + (size_t)(aoffE[l] + k1 + 32), &lds[nbuf + aldsE[l] + 512]);
    }
    __builtin_amdgcn_s_barrier();
    __builtin_amdgcn_s_setprio(1);
    #pragma unroll
    for (int m = 0; m < 4; ++m)
      #pragma unroll
      for (int n = 0; n < 4; ++n)
        acc[4 + m][n] = mfma_frag<CH>(av[m], bv[n], acc[4 + m][n]);
    __builtin_amdgcn_s_setprio(0);
    if (pf){
      asm volatile("s_waitcnt vmcnt(4)" ::: "memory");
      __builtin_amdgcn_s_barrier();
      __builtin_amdgcn_sched_barrier(0);
    }
  }

  #pragma unroll
  for (int m = 0; m < 8; ++m){
    const int row0 = by * 256 + wr * 128 + m * 16 + kg * 4;
    #pragma unroll
    for (int n = 0; n < 4; ++n){
      const int col = bx * 256 + wc * 64 + n * 16 + cl;
      #pragma unroll
      for (int j = 0; j < 4; ++j){
        const size_t off = ((size_t)(row0 + j) + (size_t)bz * CBO) * 1024 + col;
        if (EPI == 0) C[off] = acc[m][n][j];
        else if (EPI == 1){
          const float v = acc[m][n][j];
          const short hh = f2bf(v);
          Ch[off] = hh; Cl[off] = f2bf(v - bf2f(hh));
        } else {
          const float v = acc[m][n][j];
          const _Float16 hh = (_Float16)v;
          Ch[off] = __builtin_bit_cast(short, hh);
          const _Float16 ll = (_Float16)(v - (float)hh);
          Cl[off] = __builtin_bit_cast(short, ll);
        }
      }
    }
  }
}

// K3: in-place row softmax of (logits + mask[b][s]); optional fp16 copy for K4
__global__ __launch_bounds__(256) void k3_softmax(float* __restrict__ logits,
                                                  const float* __restrict__ mask,
                                                  short* __restrict__ sbf){
  const int row = blockIdx.x;       // b*TQ + t
  const int b = row >> 10;
  const int tid = threadIdx.x;
  float* p = logits + (size_t)row * DIM;
  f32x4 v  = *reinterpret_cast<const f32x4*>(p + tid * 4);
  f32x4 mk = *reinterpret_cast<const f32x4*>(mask + (size_t)b * DIM + tid * 4);
  v = v + mk;
  float mx = fmaxf(fmaxf(v[0], v[1]), fmaxf(v[2], v[3]));
  #pragma unroll
  for (int off = 32; off; off >>= 1) mx = fmaxf(mx, __shfl_xor(mx, off));
  __shared__ float red[8];
  const int lane = tid & 63, wid = tid >> 6;
  if (lane == 0) red[wid] = mx;
  __syncthreads();
  mx = fmaxf(fmaxf(red[0], red[1]), fmaxf(red[2], red[3]));
  f32x4 e;
  #pragma unroll
  for (int j = 0; j < 4; ++j) e[j] = __expf(v[j] - mx);
  float s = e[0] + e[1] + e[2] + e[3];
  #pragma unroll
  for (int off = 32; off; off >>= 1) s += __shfl_xor(s, off);
  if (lane == 0) red[4 + wid] = s;
  __syncthreads();
  s = red[4] + red[5] + red[6] + red[7];
  const float inv = 1.0f / s;
  f32x4 o;
  s16x4 ob;
  #pragma unroll
  for (int j = 0; j < 4; ++j){ o[j] = e[j] * inv; ob[j] = f2h(o[j]); }
  *reinterpret_cast<f32x4*>(p + tid * 4) = o;
  if (sbf) *reinterpret_cast<s16x4*>(sbf + (size_t)row * DIM + tid * 4) = ob;
}

// ---------------- fallback (round-3 passing) kernels ----------------

__global__ __launch_bounds__(256) void k1_qp(const float* __restrict__ A,
                                             const float* __restrict__ Wm,
                                             float* __restrict__ C){
  __shared__ __align__(16) short Ah[BM * STR];
  __shared__ __align__(16) short Al[BM * STR];
  __shared__ __align__(16) short Bh[BN * STR];
  __shared__ __align__(16) short Bl[BN * STR];
  const int tid = threadIdx.x;
  const int m0 = blockIdx.y * BM, n0 = blockIdx.x * BN;
  const int lane = tid & 63, wid = tid >> 6;
  const int wm = (wid >> 1) * 64, wn = (wid & 1) * 64;
  const int cl = lane & 15, kg = lane >> 4;
  const int rr = tid >> 3, f4 = (tid & 7) * 4;
  f32x4 acc[4][4] = {};
  for (int k0 = 0; k0 < DIM; k0 += BK){
    #pragma unroll
    for (int i = 0; i < 4; ++i){
      const int r = rr + i * 32;
      f32x4 va = *reinterpret_cast<const f32x4*>(A  + (size_t)(m0 + r) * DIM + k0 + f4);
      f32x4 vb = *reinterpret_cast<const f32x4*>(Wm + (size_t)(n0 + r) * DIM + k0 + f4);
      s16x4 ha, la, hb, lb;
      #pragma unroll
      for (int j = 0; j < 4; ++j){
        ha[j] = f2bf(va[j]); la[j] = f2bf(va[j] - bf2f(ha[j]));
        hb[j] = f2bf(vb[j]); lb[j] = f2bf(vb[j] - bf2f(hb[j]));
      }
      *reinterpret_cast<s16x4*>(&Ah[r * STR + f4]) = ha;
      *reinterpret_cast<s16x4*>(&Al[r * STR + f4]) = la;
      *reinterpret_cast<s16x4*>(&Bh[r * STR + f4]) = hb;
      *reinterpret_cast<s16x4*>(&Bl[r * STR + f4]) = lb;
    }
    __syncthreads();
    s16x8 ah[4], al8[4], bh8[4], bl8[4];
    #pragma unroll
    for (int m = 0; m < 4; ++m){
      ah[m]  = *reinterpret_cast<const s16x8*>(&Ah[(wm + m * 16 + cl) * STR + kg * 8]);
      al8[m] = *reinterpret_cast<const s16x8*>(&Al[(wm + m * 16 + cl) * STR + kg * 8]);
    }
    #pragma unroll
    for (int n = 0; n < 4; ++n){
      bh8[n] = *reinterpret_cast<const s16x8*>(&Bh[(wn + n * 16 + cl) * STR + kg * 8]);
      bl8[n] = *reinterpret_cast<const s16x8*>(&Bl[(wn + n * 16 + cl) * STR + kg * 8]);
    }
    #pragma unroll
    for (int m = 0; m < 4; ++m)
      #pragma unroll
      for (int n = 0; n < 4; ++n){
        acc[m][n] = __builtin_amdgcn_mfma_f32_16x16x32_bf16(ah[m],  bh8[n], acc[m][n], 0, 0, 0);
        acc[m][n] = __builtin_amdgcn_mfma_f32_16x16x32_bf16(al8[m], bh8[n], acc[m][n], 0, 0, 0);
        acc[m][n] = __builtin_amdgcn_mfma_f32_16x16x32_bf16(ah[m],  bl8[n], acc[m][n], 0, 0, 0);
      }
    __syncthreads();
  }
  #pragma unroll
  for (int m = 0; m < 4; ++m){
    const int row = m0 + wm + m * 16 + kg * 4;
    #pragma unroll
    for (int n = 0; n < 4; ++n){
      const int col = n0 + wn + n * 16 + cl;
      #pragma unroll
      for (int j = 0; j < 4; ++j)
        C[(size_t)(row + j) * DIM + col] = acc[m][n][j];
    }
  }
}

__global__ __launch_bounds__(256) void k2_logits(const float* __restrict__ qp,
                                                 const float* __restrict__ keys,
                                                 float* __restrict__ out){
  __shared__ __align__(16) short Ah[BM * STR];
  __shared__ __align__(16) short Al[BM * STR];
  __shared__ __align__(16) short Bh[BN * STR];
  __shared__ __align__(16) short Bl[BN * STR];
  const int tid = threadIdx.x;
  const int b = blockIdx.z;
  const int t0 = blockIdx.y * BM, s0 = blockIdx.x * BN;
  const int lane = tid & 63, wid = tid >> 6;
  const int wm = (wid >> 1) * 64, wn = (wid & 1) * 64;
  const int cl = lane & 15, kg = lane >> 4;
  const int rr = tid >> 3, f4 = (tid & 7) * 4;
  f32x4 acc[4][4] = {};
  for (int k0 = 0; k0 < DIM; k0 += BK){
    #pragma unroll
    for (int i = 0; i < 4; ++i){
      const int r = rr + i * 32;
      f32x4 va = *reinterpret_cast<const f32x4*>(qp   + (size_t)((t0 + r) * NB + b) * DIM + k0 + f4);
      f32x4 vb = *reinterpret_cast<const f32x4*>(keys + ((size_t)b * DIM + s0 + r) * DIM + k0 + f4);
      s16x4 ha, la, hb, lb;
      #pragma unroll
      for (int j = 0; j < 4; ++j){
        ha[j] = f2bf(va[j]); la[j] = f2bf(va[j] - bf2f(ha[j]));
        hb[j] = f2bf(vb[j]); lb[j] = f2bf(vb[j] - bf2f(hb[j]));
      }
      *reinterpret_cast<s16x4*>(&Ah[r * STR + f4]) = ha;
      *reinterpret_cast<s16x4*>(&Al[r * STR + f4]) = la;
      *reinterpret_cast<s16x4*>(&Bh[r * STR + f4]) = hb;
      *reinterpret_cast<s16x4*>(&Bl[r * STR + f4]) = lb;
    }
    __syncthreads();
    s16x8 ah[4], al8[4], bh8[4], bl8[4];
    #pragma unroll
    for (int m = 0; m < 4; ++m){
      ah[m]  = *reinterpret_cast<const s16x8*>(&Ah[(wm + m * 16 + cl) * STR + kg * 8]);
      al8[m] = *reinterpret_cast<const s16x8*>(&Al[(wm + m * 16 + cl) * STR + kg * 8]);
    }
    #pragma unroll
    for (int n = 0; n < 4; ++n){
      bh8[n] = *reinterpret_cast<const s16x8*>(&Bh[(wn + n * 16 + cl) * STR + kg * 8]);
      bl8[n] = *reinterpret_cast<const s16x8*>(&Bl[(wn + n * 16 + cl) * STR + kg * 8]);
    }
    #pragma unroll
    for (int m = 0; m < 4; ++m)
      #pragma unroll
      for (int n = 0; n < 4; ++n){
        acc[m][n] = __builtin_amdgcn_mfma_f32_16x16x32_bf16(ah[m],  bh8[n], acc[m][n], 0, 0, 0);
        acc[m][n] = __builtin_amdgcn_mfma_f32_16x16x32_bf16(al8[m], bh8[n], acc[m][n], 0, 0, 0);
        acc[m][n] = __builtin_amdgcn_mfma_f32_16x16x32_bf16(ah[m],  bl8[n], acc[m][n], 0, 0, 0);
      }
    __syncthreads();
  }
  #pragma unroll
  for (int m = 0; m < 4; ++m){
    const int trow = t0 + wm + m * 16 + kg * 4;
    #pragma unroll
    for (int n = 0; n < 4; ++n){
      const int scol = s0 + wn + n * 16 + cl;
      #pragma unroll
      for (int j = 0; j < 4; ++j)
        out[((size_t)b * TQn + trow + j) * DIM + scol] = acc[m][n][j];
    }
  }
}

__global__ __launch_bounds__(256) void k4_ctx(const float* __restrict__ score,
                                              const float* __restrict__ values,
                                              float* __restrict__ ctx){
  __shared__ __align__(16) short As[BM * STR];
  __shared__ __align__(16) float Vs[BK * VSTR];
  const int tid = threadIdx.x;
  const int b = blockIdx.z;
  const int t0 = blockIdx.y * BM, v0 = blockIdx.x * BN;
  const int lane = tid & 63, wid = tid >> 6;
  const int wm = (wid >> 1) * 64, wn = (wid & 1) * 64;
  const int cl = lane & 15, kg = lane >> 4;
  const int rr = tid >> 3, f4 = (tid & 7) * 4;
  const int vr = tid >> 5, vc = tid & 31;
  f32x4 acc[4][4] = {};
  for (int k0 = 0; k0 < DIM; k0 += BK){
    #pragma unroll
    for (int i = 0; i < 4; ++i){
      const int r = rr + i * 32;
      f32x4 va = *reinterpret_cast<const f32x4*>(score + ((size_t)b * TQn + t0 + r) * DIM + k0 + f4);
      s16x4 ha;
      #pragma unroll
      for (int j = 0; j < 4; ++j) ha[j] = f2bf(va[j]);
      *reinterpret_cast<s16x4*>(&As[r * STR + f4]) = ha;
      const int vrow = vr + i * 8;
      f32x4 vv = *reinterpret_cast<const f32x4*>(values + ((size_t)b * DIM + k0 + vrow) * DIM + v0 + vc * 4);
      const int cb = vc ^ (((vrow >> 3) & 1) << 2);
      *reinterpret_cast<f32x4*>(&Vs[vrow * VSTR + cb * 4]) = vv;
    }
    __syncthreads();
    s16x8 af[4], bfr[4];
    #pragma unroll
    for (int m = 0; m < 4; ++m)
      af[m] = *reinterpret_cast<const s16x8*>(&As[(wm + m * 16 + cl) * STR + kg * 8]);
    #pragma unroll
    for (int n = 0; n < 4; ++n){
      const int colb = wn + n * 16 + cl;
      const int cb = (colb >> 2) ^ ((kg & 1) << 2);
      #pragma unroll
      for (int j = 0; j < 8; ++j){
        const int rowv = kg * 8 + j;
        bfr[n][j] = f2bf(Vs[rowv * VSTR + cb * 4 + (colb & 3)]);
      }
    }
    #pragma unroll
    for (int m = 0; m < 4; ++m)
      #pragma unroll
      for (int n = 0; n < 4; ++n)
        acc[m][n] = __builtin_amdgcn_mfma_f32_16x16x32_bf16(af[m], bfr[n], acc[m][n], 0, 0, 0);
    __syncthreads();
  }
  #pragma unroll
  for (int m = 0; m < 4; ++m){
    const int trow = t0 + wm + m * 16 + kg * 4;
    #pragma unroll
    for (int n = 0; n < 4; ++n){
      const int vcol = v0 + wn + n * 16 + cl;
      #pragma unroll
      for (int j = 0; j < 4; ++j)
        ctx[((size_t)b * TQn + trow + j) * DIM + vcol] = acc[m][n][j];
    }
  }
}

extern "C" void kernel_launch(void* const* d_in, const int* in_sizes, int n_in,
                              void* d_out, int out_size, void* d_ws, size_t ws_size,
                              hipStream_t stream){
  (void)in_sizes; (void)n_in; (void)out_size;
  const float* query  = (const float*)d_in[0];  // [1024][16][1024] == m-major [16384][1024]
  const float* keys   = (const float*)d_in[1];  // [16][1024][1024]
  const float* values = (const float*)d_in[2];  // [16][1024][1024]
  const float* mask   = (const float*)d_in[3];  // [16][1024]
  const float* Wm     = (const float*)d_in[4];  // [1024][1024]
  float* score = (float*)d_out;                              // [16][1024][1024]
  float* ctx   = score + (size_t)NB * TQn * DIM;             // qp-plane scratch then real ctx
  dim3 blk(256, 1, 1);
  dim3 blk512(512, 1, 1);

  const size_t M16 = (size_t)16 * 1024 * 1024;   // 16M shorts
  const size_t M1  = (size_t)1024 * 1024;
  const size_t need = (4 * M16 + M1) * 2;        // 130 MB
  if (ws_size >= need){
    short* w  = (short*)d_ws;
    short* qf = w;                 // query fp16 (single plane)
    short* kf = qf + M16;          // keys fp16 (single plane)
    short* wf = kf + M16;          // W fp16 (single plane)
    short* vT = wf + M1;           // values^T fp16 [b][v][s]
    short* sb = vT + M16;          // score fp16
    short* qph = (short*)ctx;      // qp fp16 hi plane (m-major [16384][1024])
    short* qpl = qph + M16;        // qp fp16 lo plane

    k0_cvt16<<<dim3(16384, 1, 1), blk, 0, stream>>>(query, qf);
    k0_cvt16<<<dim3(16384, 1, 1), blk, 0, stream>>>(keys, kf);
    k0_cvt16<<<dim3(1024, 1, 1), blk, 0, stream>>>(Wm, wf);
    k0_vtrans<<<dim3(16, 16, 16), blk, 0, stream>>>(values, vT);
    // K1: qp = qf . wf^T  (fp16 1-chain) -> fp16 hi/lo planes
    gemm256<4, 2><<<dim3(4, 64, 1), blk512, 0, stream>>>(qf, nullptr, wf, nullptr,
        nullptr, qph, qpl, 1, 0, 1, 0, 0);
    // K2: logits = (qph+qpl) . kf  (fp16 2-chain)
    gemm256<2, 0><<<dim3(4, 4, 16), blk512, 0, stream>>>(qph, qpl, kf, nullptr,
        score, nullptr, nullptr, 16, 1, 1, 1024, 1024);
    k3_softmax<<<dim3(NB * TQn, 1, 1), blk, 0, stream>>>(score, mask, sb);
    // K4: ctx = sb . vT  (fp16 1-chain)
    gemm256<4, 0><<<dim3(4, 4, 16), blk512, 0, stream>>>(sb, nullptr, vT, nullptr,
        ctx, nullptr, nullptr, 1, 1024, 1, 1024, 1024);
  } else {
    k1_qp<<<dim3(DIM / BN, (TQn * NB) / BM, 1), blk, 0, stream>>>(query, Wm, ctx);
    k2_logits<<<dim3(DIM / BN, TQn / BM, NB), blk, 0, stream>>>(ctx, keys, score);
    k3_softmax<<<dim3(NB * TQn, 1, 1), blk, 0, stream>>>(score, mask, nullptr);
    k4_ctx<<<dim3(DIM / BN, TQn / BM, NB), blk, 0, stream>>>(score, values, ctx);
  }
}

// Round 12
// 234.216 us; speedup vs baseline: 1.7663x; 1.1466x over previous
//
#include <hip/hip_runtime.h>
#include <hip/hip_bf16.h>

#define TQn 1024
#define NB  16
#define DIM 1024
#define BM  128
#define BN  128
#define BK  32
#define STR 40
#define VSTR 132

typedef __attribute__((ext_vector_type(4))) float f32x4;
typedef __attribute__((ext_vector_type(8))) short s16x8;
typedef __attribute__((ext_vector_type(4))) short s16x4;
typedef __attribute__((ext_vector_type(8))) _Float16 h16x8;

__device__ __forceinline__ short f2bf(float f){
  union { float f; unsigned u; } v; v.f = f;
  unsigned r = v.u + 0x7fffu + ((v.u >> 16) & 1u);  // RNE
  return (short)(r >> 16);
}
__device__ __forceinline__ float bf2f(short h){
  union { unsigned u; float f; } v; v.u = ((unsigned)(unsigned short)h) << 16;
  return v.f;
}
__device__ __forceinline__ short f2h(float f){
  _Float16 h = (_Float16)f;
  return __builtin_bit_cast(short, h);
}

__device__ __forceinline__ void gload16(const short* g, short* l){
#if __has_builtin(__builtin_amdgcn_global_load_lds)
  __builtin_amdgcn_global_load_lds(
      (const __attribute__((address_space(1))) unsigned int*)(const void*)g,
      (__attribute__((address_space(3))) unsigned int*)(void*)l, 16, 0, 0);
#else
  *reinterpret_cast<s16x8*>(l) = *reinterpret_cast<const s16x8*>(g);
#endif
}

// CH=2 (fp16 2-chain) and CH=4 (fp16 1-chain) use fp16 MFMA; CH=1/3 bf16.
template<int CH>
__device__ __forceinline__ f32x4 mfma_frag(s16x8 a, s16x8 b, f32x4 c){
  if constexpr (CH == 2 || CH == 4)
    return __builtin_amdgcn_mfma_f32_16x16x32_f16(
        __builtin_bit_cast(h16x8, a), __builtin_bit_cast(h16x8, b), c, 0, 0, 0);
  else
    return __builtin_amdgcn_mfma_f32_16x16x32_bf16(a, b, c, 0, 0, 0);
}

// ---------------- fast path ----------------

// fp32 -> single fp16 plane
__global__ __launch_bounds__(256) void k0_cvt16(const float* __restrict__ in,
                                                short* __restrict__ out){
  const size_t i = ((size_t)blockIdx.x * 256 + threadIdx.x) * 4;
  f32x4 v = *reinterpret_cast<const f32x4*>(in + i);
  s16x4 o;
  #pragma unroll
  for (int j = 0; j < 4; ++j) o[j] = f2h(v[j]);
  *reinterpret_cast<s16x4*>(out + i) = o;
}

// values [b][s][v] fp32 -> vT [b][v][s] fp16
__global__ __launch_bounds__(256) void k0_vtrans(const float* __restrict__ vals,
                                                 short* __restrict__ vT){
  __shared__ short T[64 * 72];
  const int t = threadIdx.x;
  const int v0 = blockIdx.x * 64, s0 = blockIdx.y * 64, b = blockIdx.z;
  const int r16 = t >> 4, c4 = (t & 15) * 4;
  #pragma unroll
  for (int i = 0; i < 4; ++i){
    const int sl = i * 16 + r16;
    f32x4 v = *reinterpret_cast<const f32x4*>(vals + ((size_t)b * TQn + s0 + sl) * DIM + v0 + c4);
    #pragma unroll
    for (int j = 0; j < 4; ++j) T[(c4 + j) * 72 + sl] = f2h(v[j]);
  }
  __syncthreads();
  #pragma unroll
  for (int i = 0; i < 4; ++i){
    const int vl = i * 16 + r16;
    s16x4 o = *reinterpret_cast<const s16x4*>(&T[vl * 72 + c4]);
    *reinterpret_cast<s16x4*>(vT + ((size_t)b * DIM + v0 + vl) * TQn + s0 + c4) = o;
  }
}

// 256x256 A*B^T GEMM, 8 waves (2Mx4N), BK=64, dbuf 128KB, fragment-major
// (conflict-free b128), counted-vmcnt pipeline (round-8 proven structure).
// CH=3: bf16 virtual-K 3x1024 ; CH=2: fp16 2x1024 (A hi/lo, B single)
// CH=1: bf16 plain 1024 ; CH=4: fp16 plain 1024
// EPI: 0 = fp32 C; 1 = bf16 hi/lo planes; 2 = fp16 hi/lo planes; 3 = fp16 single plane
template<int CH, int EPI>
__global__ __launch_bounds__(512, 2) void gemm256(
    const short* __restrict__ Ah, const short* __restrict__ Al,
    const short* __restrict__ Bh, const short* __restrict__ Bl,
    float* __restrict__ C, short* __restrict__ Ch, short* __restrict__ Cl,
    int ARS, int ABO, int BRS, int BBO, int CBO)
{
  constexpr int NSTEP = (CH == 3) ? 48 : (CH == 2) ? 32 : 16;
  __shared__ __align__(16) short lds[2 * 32768];   // 128 KB
  const int tid = threadIdx.x;
  const int lane = tid & 63, w = tid >> 6;
  const int cl = lane & 15, kg = lane >> 4;
  const int lane8 = lane * 8;
  const int bx = blockIdx.x, by = blockIdx.y, bz = blockIdx.z;
  const int wr = w >> 2, wc = w & 3;

  int aoffE[2], boffE[2], aldsE[2], bldsE[2];
  #pragma unroll
  for (int l = 0; l < 2; ++l){
    const int rg = 2 * w + l;
    const int arow = by * 256 + rg * 16 + cl;
    const int brow = bx * 256 + rg * 16 + cl;
    aoffE[l] = (arow * ARS + bz * ABO) * 1024 + kg * 8;
    boffE[l] = (brow * BRS + bz * BBO) * 1024 + kg * 8;
    aldsE[l] = (4 * w + 2 * l) * 512 + lane8;
    bldsE[l] = 16384 + (4 * w + 2 * l) * 512 + lane8;
  }

  f32x4 acc[8][4] = {};

  // prologue: stage tile 0 (chain 0 -> Ah,Bh) in deadline order; kk1 stays in flight.
  #pragma unroll
  for (int l = 0; l < 2; ++l) gload16(Bh + (size_t)boffE[l], &lds[bldsE[l]]);
  #pragma unroll
  for (int l = 0; l < 2; ++l) gload16(Ah + (size_t)aoffE[l], &lds[aldsE[l]]);
  #pragma unroll
  for (int l = 0; l < 2; ++l) gload16(Bh + (size_t)(boffE[l] + 32), &lds[bldsE[l] + 512]);
  #pragma unroll
  for (int l = 0; l < 2; ++l) gload16(Ah + (size_t)(aoffE[l] + 32), &lds[aldsE[l] + 512]);
  asm volatile("s_waitcnt vmcnt(4)" ::: "memory");
  __builtin_amdgcn_s_barrier();
  __builtin_amdgcn_sched_barrier(0);

  for (int t = 0; t < NSTEP; ++t){
    const int buf = (t & 1) * 32768;
    const int nbuf = buf ^ 32768;
    const bool pf = (t + 1 < NSTEP);
    int k1 = 0; const short *PA = Ah, *PB = Bh;
    if (pf){
      if (CH == 3){
        const int cc = (t + 1) % 3;
        k1 = ((t + 1) / 3) * 64;
        PA = (cc == 1) ? Al : Ah;
        PB = (cc == 2) ? Bl : Bh;
      } else if (CH == 2){
        k1 = ((t + 1) >> 1) * 64;
        PA = ((t + 1) & 1) ? Al : Ah;
        PB = Bh;
      } else k1 = (t + 1) * 64;
    }

    s16x8 av[4], bv[4];
    // ---- ph0: quad (m0-3, kk0) ----
    #pragma unroll
    for (int m = 0; m < 4; ++m)
      av[m] = *reinterpret_cast<const s16x8*>(&lds[buf + ((wr * 8 + m) * 2 + 0) * 512 + lane8]);
    #pragma unroll
    for (int n = 0; n < 4; ++n)
      bv[n] = *reinterpret_cast<const s16x8*>(&lds[buf + 16384 + ((wc * 4 + n) * 2 + 0) * 512 + lane8]);
    if (pf){
      #pragma unroll
      for (int l = 0; l < 2; ++l) gload16(PB + (size_t)(boffE[l] + k1), &lds[nbuf + bldsE[l]]);
    }
    __builtin_amdgcn_s_barrier();
    __builtin_amdgcn_s_setprio(1);
    #pragma unroll
    for (int m = 0; m < 4; ++m)
      #pragma unroll
      for (int n = 0; n < 4; ++n)
        acc[m][n] = mfma_frag<CH>(av[m], bv[n], acc[m][n]);
    __builtin_amdgcn_s_setprio(0);
    __builtin_amdgcn_s_barrier();
    // ---- ph1: quad (m4-7, kk0), bv reused ----
    #pragma unroll
    for (int m = 0; m < 4; ++m)
      av[m] = *reinterpret_cast<const s16x8*>(&lds[buf + ((wr * 8 + 4 + m) * 2 + 0) * 512 + lane8]);
    if (pf){
      #pragma unroll
      for (int l = 0; l < 2; ++l) gload16(PA + (size_t)(aoffE[l] + k1), &lds[nbuf + aldsE[l]]);
    }
    __builtin_amdgcn_s_barrier();
    __builtin_amdgcn_s_setprio(1);
    #pragma unroll
    for (int m = 0; m < 4; ++m)
      #pragma unroll
      for (int n = 0; n < 4; ++n)
        acc[4 + m][n] = mfma_frag<CH>(av[m], bv[n], acc[4 + m][n]);
    __builtin_amdgcn_s_setprio(0);
    if (pf) asm volatile("s_waitcnt vmcnt(4)" ::: "memory");
    else    asm volatile("s_waitcnt vmcnt(0)" ::: "memory");
    __builtin_amdgcn_s_barrier();
    __builtin_amdgcn_sched_barrier(0);
    // ---- ph2: quad (m0-3, kk1) ----
    #pragma unroll
    for (int m = 0; m < 4; ++m)
      av[m] = *reinterpret_cast<const s16x8*>(&lds[buf + ((wr * 8 + m) * 2 + 1) * 512 + lane8]);
    #pragma unroll
    for (int n = 0; n < 4; ++n)
      bv[n] = *reinterpret_cast<const s16x8*>(&lds[buf + 16384 + ((wc * 4 + n) * 2 + 1) * 512 + lane8]);
    if (pf){
      #pragma unroll
      for (int l = 0; l < 2; ++l) gload16(PB + (size_t)(boffE[l] + k1 + 32), &lds[nbuf + bldsE[l] + 512]);
    }
    __builtin_amdgcn_s_barrier();
    __builtin_amdgcn_s_setprio(1);
    #pragma unroll
    for (int m = 0; m < 4; ++m)
      #pragma unroll
      for (int n = 0; n < 4; ++n)
        acc[m][n] = mfma_frag<CH>(av[m], bv[n], acc[m][n]);
    __builtin_amdgcn_s_setprio(0);
    __builtin_amdgcn_s_barrier();
    // ---- ph3: quad (m4-7, kk1), bv reused ----
    #pragma unroll
    for (int m = 0; m < 4; ++m)
      av[m] = *reinterpret_cast<const s16x8*>(&lds[buf + ((wr * 8 + 4 + m) * 2 + 1) * 512 + lane8]);
    if (pf){
      #pragma unroll
      for (int l = 0; l < 2; ++l) gload16(PA + (size_t)(aoffE[l] + k1 + 32), &lds[nbuf + aldsE[l] + 512]);
    }
    __builtin_amdgcn_s_barrier();
    __builtin_amdgcn_s_setprio(1);
    #pragma unroll
    for (int m = 0; m < 4; ++m)
      #pragma unroll
      for (int n = 0; n < 4; ++n)
        acc[4 + m][n] = mfma_frag<CH>(av[m], bv[n], acc[4 + m][n]);
    __builtin_amdgcn_s_setprio(0);
    if (pf){
      asm volatile("s_waitcnt vmcnt(4)" ::: "memory");
      __builtin_amdgcn_s_barrier();
      __builtin_amdgcn_sched_barrier(0);
    }
  }

  #pragma unroll
  for (int m = 0; m < 8; ++m){
    const int row0 = by * 256 + wr * 128 + m * 16 + kg * 4;
    #pragma unroll
    for (int n = 0; n < 4; ++n){
      const int col = bx * 256 + wc * 64 + n * 16 + cl;
      #pragma unroll
      for (int j = 0; j < 4; ++j){
        const size_t off = ((size_t)(row0 + j) + (size_t)bz * CBO) * 1024 + col;
        if (EPI == 0) C[off] = acc[m][n][j];
        else if (EPI == 1){
          const float v = acc[m][n][j];
          const short hh = f2bf(v);
          Ch[off] = hh; Cl[off] = f2bf(v - bf2f(hh));
        } else if (EPI == 2){
          const float v = acc[m][n][j];
          const _Float16 hh = (_Float16)v;
          Ch[off] = __builtin_bit_cast(short, hh);
          const _Float16 ll = (_Float16)(v - (float)hh);
          Cl[off] = __builtin_bit_cast(short, ll);
        } else {
          Ch[off] = f2h(acc[m][n][j]);
        }
      }
    }
  }
}

// K3: in-place row softmax of (logits + mask[b][s]); optional fp16 copy for K4
__global__ __launch_bounds__(256) void k3_softmax(float* __restrict__ logits,
                                                  const float* __restrict__ mask,
                                                  short* __restrict__ sbf){
  const int row = blockIdx.x;       // b*TQ + t
  const int b = row >> 10;
  const int tid = threadIdx.x;
  float* p = logits + (size_t)row * DIM;
  f32x4 v  = *reinterpret_cast<const f32x4*>(p + tid * 4);
  f32x4 mk = *reinterpret_cast<const f32x4*>(mask + (size_t)b * DIM + tid * 4);
  v = v + mk;
  float mx = fmaxf(fmaxf(v[0], v[1]), fmaxf(v[2], v[3]));
  #pragma unroll
  for (int off = 32; off; off >>= 1) mx = fmaxf(mx, __shfl_xor(mx, off));
  __shared__ float red[8];
  const int lane = tid & 63, wid = tid >> 6;
  if (lane == 0) red[wid] = mx;
  __syncthreads();
  mx = fmaxf(fmaxf(red[0], red[1]), fmaxf(red[2], red[3]));
  f32x4 e;
  #pragma unroll
  for (int j = 0; j < 4; ++j) e[j] = __expf(v[j] - mx);
  float s = e[0] + e[1] + e[2] + e[3];
  #pragma unroll
  for (int off = 32; off; off >>= 1) s += __shfl_xor(s, off);
  if (lane == 0) red[4 + wid] = s;
  __syncthreads();
  s = red[4] + red[5] + red[6] + red[7];
  const float inv = 1.0f / s;
  f32x4 o;
  s16x4 ob;
  #pragma unroll
  for (int j = 0; j < 4; ++j){ o[j] = e[j] * inv; ob[j] = f2h(o[j]); }
  *reinterpret_cast<f32x4*>(p + tid * 4) = o;
  if (sbf) *reinterpret_cast<s16x4*>(sbf + (size_t)row * DIM + tid * 4) = ob;
}

// ---------------- fallback (round-3 passing) kernels ----------------

__global__ __launch_bounds__(256) void k1_qp(const float* __restrict__ A,
                                             const float* __restrict__ Wm,
                                             float* __restrict__ C){
  __shared__ __align__(16) short Ah[BM * STR];
  __shared__ __align__(16) short Al[BM * STR];
  __shared__ __align__(16) short Bh[BN * STR];
  __shared__ __align__(16) short Bl[BN * STR];
  const int tid = threadIdx.x;
  const int m0 = blockIdx.y * BM, n0 = blockIdx.x * BN;
  const int lane = tid & 63, wid = tid >> 6;
  const int wm = (wid >> 1) * 64, wn = (wid & 1) * 64;
  const int cl = lane & 15, kg = lane >> 4;
  const int rr = tid >> 3, f4 = (tid & 7) * 4;
  f32x4 acc[4][4] = {};
  for (int k0 = 0; k0 < DIM; k0 += BK){
    #pragma unroll
    for (int i = 0; i < 4; ++i){
      const int r = rr + i * 32;
      f32x4 va = *reinterpret_cast<const f32x4*>(A  + (size_t)(m0 + r) * DIM + k0 + f4);
      f32x4 vb = *reinterpret_cast<const f32x4*>(Wm + (size_t)(n0 + r) * DIM + k0 + f4);
      s16x4 ha, la, hb, lb;
      #pragma unroll
      for (int j = 0; j < 4; ++j){
        ha[j] = f2bf(va[j]); la[j] = f2bf(va[j] - bf2f(ha[j]));
        hb[j] = f2bf(vb[j]); lb[j] = f2bf(vb[j] - bf2f(hb[j]));
      }
      *reinterpret_cast<s16x4*>(&Ah[r * STR + f4]) = ha;
      *reinterpret_cast<s16x4*>(&Al[r * STR + f4]) = la;
      *reinterpret_cast<s16x4*>(&Bh[r * STR + f4]) = hb;
      *reinterpret_cast<s16x4*>(&Bl[r * STR + f4]) = lb;
    }
    __syncthreads();
    s16x8 ah[4], al8[4], bh8[4], bl8[4];
    #pragma unroll
    for (int m = 0; m < 4; ++m){
      ah[m]  = *reinterpret_cast<const s16x8*>(&Ah[(wm + m * 16 + cl) * STR + kg * 8]);
      al8[m] = *reinterpret_cast<const s16x8*>(&Al[(wm + m * 16 + cl) * STR + kg * 8]);
    }
    #pragma unroll
    for (int n = 0; n < 4; ++n){
      bh8[n] = *reinterpret_cast<const s16x8*>(&Bh[(wn + n * 16 + cl) * STR + kg * 8]);
      bl8[n] = *reinterpret_cast<const s16x8*>(&Bl[(wn + n * 16 + cl) * STR + kg * 8]);
    }
    #pragma unroll
    for (int m = 0; m < 4; ++m)
      #pragma unroll
      for (int n = 0; n < 4; ++n){
        acc[m][n] = __builtin_amdgcn_mfma_f32_16x16x32_bf16(ah[m],  bh8[n], acc[m][n], 0, 0, 0);
        acc[m][n] = __builtin_amdgcn_mfma_f32_16x16x32_bf16(al8[m], bh8[n], acc[m][n], 0, 0, 0);
        acc[m][n] = __builtin_amdgcn_mfma_f32_16x16x32_bf16(ah[m],  bl8[n], acc[m][n], 0, 0, 0);
      }
    __syncthreads();
  }
  #pragma unroll
  for (int m = 0; m < 4; ++m){
    const int row = m0 + wm + m * 16 + kg * 4;
    #pragma unroll
    for (int n = 0; n < 4; ++n){
      const int col = n0 + wn + n * 16 + cl;
      #pragma unroll
      for (int j = 0; j < 4; ++j)
        C[(size_t)(row + j) * DIM + col] = acc[m][n][j];
    }
  }
}

__global__ __launch_bounds__(256) void k2_logits(const float* __restrict__ qp,
                                                 const float* __restrict__ keys,
                                                 float* __restrict__ out){
  __shared__ __align__(16) short Ah[BM * STR];
  __shared__ __align__(16) short Al[BM * STR];
  __shared__ __align__(16) short Bh[BN * STR];
  __shared__ __align__(16) short Bl[BN * STR];
  const int tid = threadIdx.x;
  const int b = blockIdx.z;
  const int t0 = blockIdx.y * BM, s0 = blockIdx.x * BN;
  const int lane = tid & 63, wid = tid >> 6;
  const int wm = (wid >> 1) * 64, wn = (wid & 1) * 64;
  const int cl = lane & 15, kg = lane >> 4;
  const int rr = tid >> 3, f4 = (tid & 7) * 4;
  f32x4 acc[4][4] = {};
  for (int k0 = 0; k0 < DIM; k0 += BK){
    #pragma unroll
    for (int i = 0; i < 4; ++i){
      const int r = rr + i * 32;
      f32x4 va = *reinterpret_cast<const f32x4*>(qp   + (size_t)((t0 + r) * NB + b) * DIM + k0 + f4);
      f32x4 vb = *reinterpret_cast<const f32x4*>(keys + ((size_t)b * DIM + s0 + r) * DIM + k0 + f4);
      s16x4 ha, la, hb, lb;
      #pragma unroll
      for (int j = 0; j < 4; ++j){
        ha[j] = f2bf(va[j]); la[j] = f2bf(va[j] - bf2f(ha[j]));
        hb[j] = f2bf(vb[j]); lb[j] = f2bf(vb[j] - bf2f(hb[j]));
      }
      *reinterpret_cast<s16x4*>(&Ah[r * STR + f4]) = ha;
      *reinterpret_cast<s16x4*>(&Al[r * STR + f4]) = la;
      *reinterpret_cast<s16x4*>(&Bh[r * STR + f4]) = hb;
      *reinterpret_cast<s16x4*>(&Bl[r * STR + f4]) = lb;
    }
    __syncthreads();
    s16x8 ah[4], al8[4], bh8[4], bl8[4];
    #pragma unroll
    for (int m = 0; m < 4; ++m){
      ah[m]  = *reinterpret_cast<const s16x8*>(&Ah[(wm + m * 16 + cl) * STR + kg * 8]);
      al8[m] = *reinterpret_cast<const s16x8*>(&Al[(wm + m * 16 + cl) * STR + kg * 8]);
    }
    #pragma unroll
    for (int n = 0; n < 4; ++n){
      bh8[n] = *reinterpret_cast<const s16x8*>(&Bh[(wn + n * 16 + cl) * STR + kg * 8]);
      bl8[n] = *reinterpret_cast<const s16x8*>(&Bl[(wn + n * 16 + cl) * STR + kg * 8]);
    }
    #pragma unroll
    for (int m = 0; m < 4; ++m)
      #pragma unroll
      for (int n = 0; n < 4; ++n){
        acc[m][n] = __builtin_amdgcn_mfma_f32_16x16x32_bf16(ah[m],  bh8[n], acc[m][n], 0, 0, 0);
        acc[m][n] = __builtin_amdgcn_mfma_f32_16x16x32_bf16(al8[m], bh8[n], acc[m][n], 0, 0, 0);
        acc[m][n] = __builtin_amdgcn_mfma_f32_16x16x32_bf16(ah[m],  bl8[n], acc[m][n], 0, 0, 0);
      }
    __syncthreads();
  }
  #pragma unroll
  for (int m = 0; m < 4; ++m){
    const int trow = t0 + wm + m * 16 + kg * 4;
    #pragma unroll
    for (int n = 0; n < 4; ++n){
      const int scol = s0 + wn + n * 16 + cl;
      #pragma unroll
      for (int j = 0; j < 4; ++j)
        out[((size_t)b * TQn + trow + j) * DIM + scol] = acc[m][n][j];
    }
  }
}

__global__ __launch_bounds__(256) void k4_ctx(const float* __restrict__ score,
                                              const float* __restrict__ values,
                                              float* __restrict__ ctx){
  __shared__ __align__(16) short As[BM * STR];
  __shared__ __align__(16) float Vs[BK * VSTR];
  const int tid = threadIdx.x;
  const int b = blockIdx.z;
  const int t0 = blockIdx.y * BM, v0 = blockIdx.x * BN;
  const int lane = tid & 63, wid = tid >> 6;
  const int wm = (wid >> 1) * 64, wn = (wid & 1) * 64;
  const int cl = lane & 15, kg = lane >> 4;
  const int rr = tid >> 3, f4 = (tid & 7) * 4;
  const int vr = tid >> 5, vc = tid & 31;
  f32x4 acc[4][4] = {};
  for (int k0 = 0; k0 < DIM; k0 += BK){
    #pragma unroll
    for (int i = 0; i < 4; ++i){
      const int r = rr + i * 32;
      f32x4 va = *reinterpret_cast<const f32x4*>(score + ((size_t)b * TQn + t0 + r) * DIM + k0 + f4);
      s16x4 ha;
      #pragma unroll
      for (int j = 0; j < 4; ++j) ha[j] = f2bf(va[j]);
      *reinterpret_cast<s16x4*>(&As[r * STR + f4]) = ha;
      const int vrow = vr + i * 8;
      f32x4 vv = *reinterpret_cast<const f32x4*>(values + ((size_t)b * DIM + k0 + vrow) * DIM + v0 + vc * 4);
      const int cb = vc ^ (((vrow >> 3) & 1) << 2);
      *reinterpret_cast<f32x4*>(&Vs[vrow * VSTR + cb * 4]) = vv;
    }
    __syncthreads();
    s16x8 af[4], bfr[4];
    #pragma unroll
    for (int m = 0; m < 4; ++m)
      af[m] = *reinterpret_cast<const s16x8*>(&As[(wm + m * 16 + cl) * STR + kg * 8]);
    #pragma unroll
    for (int n = 0; n < 4; ++n){
      const int colb = wn + n * 16 + cl;
      const int cb = (colb >> 2) ^ ((kg & 1) << 2);
      #pragma unroll
      for (int j = 0; j < 8; ++j){
        const int rowv = kg * 8 + j;
        bfr[n][j] = f2bf(Vs[rowv * VSTR + cb * 4 + (colb & 3)]);
      }
    }
    #pragma unroll
    for (int m = 0; m < 4; ++m)
      #pragma unroll
      for (int n = 0; n < 4; ++n)
        acc[m][n] = __builtin_amdgcn_mfma_f32_16x16x32_bf16(af[m], bfr[n], acc[m][n], 0, 0, 0);
    __syncthreads();
  }
  #pragma unroll
  for (int m = 0; m < 4; ++m){
    const int trow = t0 + wm + m * 16 + kg * 4;
    #pragma unroll
    for (int n = 0; n < 4; ++n){
      const int vcol = v0 + wn + n * 16 + cl;
      #pragma unroll
      for (int j = 0; j < 4; ++j)
        ctx[((size_t)b * TQn + trow + j) * DIM + vcol] = acc[m][n][j];
    }
  }
}

extern "C" void kernel_launch(void* const* d_in, const int* in_sizes, int n_in,
                              void* d_out, int out_size, void* d_ws, size_t ws_size,
                              hipStream_t stream){
  (void)in_sizes; (void)n_in; (void)out_size;
  const float* query  = (const float*)d_in[0];  // [1024][16][1024] == m-major [16384][1024]
  const float* keys   = (const float*)d_in[1];  // [16][1024][1024]
  const float* values = (const float*)d_in[2];  // [16][1024][1024]
  const float* mask   = (const float*)d_in[3];  // [16][1024]
  const float* Wm     = (const float*)d_in[4];  // [1024][1024]
  float* score = (float*)d_out;                              // [16][1024][1024]
  float* ctx   = score + (size_t)NB * TQn * DIM;             // qp-plane scratch then real ctx
  dim3 blk(256, 1, 1);
  dim3 blk512(512, 1, 1);

  const size_t M16 = (size_t)16 * 1024 * 1024;   // 16M shorts
  const size_t M1  = (size_t)1024 * 1024;
  const size_t need = (4 * M16 + M1) * 2;        // 130 MB
  if (ws_size >= need){
    short* w  = (short*)d_ws;
    short* qf = w;                 // query fp16 (single plane)
    short* kf = qf + M16;          // keys fp16 (single plane)
    short* wf = kf + M16;          // W fp16 (single plane)
    short* vT = wf + M1;           // values^T fp16 [b][v][s]
    short* sb = vT + M16;          // score fp16
    short* qph = (short*)ctx;      // qp fp16 single plane (m-major [16384][1024])

    k0_cvt16<<<dim3(16384, 1, 1), blk, 0, stream>>>(query, qf);
    k0_cvt16<<<dim3(16384, 1, 1), blk, 0, stream>>>(keys, kf);
    k0_cvt16<<<dim3(1024, 1, 1), blk, 0, stream>>>(Wm, wf);
    k0_vtrans<<<dim3(16, 16, 16), blk, 0, stream>>>(values, vT);
    // K1: qp = qf . wf^T  (fp16 1-chain) -> fp16 single plane
    gemm256<4, 3><<<dim3(4, 64, 1), blk512, 0, stream>>>(qf, nullptr, wf, nullptr,
        nullptr, qph, nullptr, 1, 0, 1, 0, 0);
    // K2: logits = qph . kf  (fp16 1-chain)
    gemm256<4, 0><<<dim3(4, 4, 16), blk512, 0, stream>>>(qph, nullptr, kf, nullptr,
        score, nullptr, nullptr, 16, 1, 1, 1024, 1024);
    k3_softmax<<<dim3(NB * TQn, 1, 1), blk, 0, stream>>>(score, mask, sb);
    // K4: ctx = sb . vT  (fp16 1-chain)
    gemm256<4, 0><<<dim3(4, 4, 16), blk512, 0, stream>>>(sb, nullptr, vT, nullptr,
        ctx, nullptr, nullptr, 1, 1024, 1, 1024, 1024);
  } else {
    k1_qp<<<dim3(DIM / BN, (TQn * NB) / BM, 1), blk, 0, stream>>>(query, Wm, ctx);
    k2_logits<<<dim3(DIM / BN, TQn / BM, NB), blk, 0, stream>>>(ctx, keys, score);
    k3_softmax<<<dim3(NB * TQn, 1, 1), blk, 0, stream>>>(score, mask, nullptr);
    k4_ctx<<<dim3(DIM / BN, TQn / BM, NB), blk, 0, stream>>>(score, values, ctx);
  }
}